// Round 1
// baseline (307.502 us; speedup 1.0000x reference)
//
#include <hip/hip_runtime.h>
#include <stdint.h>

typedef unsigned short u16;
typedef u16   us8    __attribute__((ext_vector_type(8)));
typedef __bf16 bf16x8 __attribute__((ext_vector_type(8)));
typedef float f32x4  __attribute__((ext_vector_type(4)));

#define DEV static __device__ __forceinline__

DEV u16 f2bf(float f) {                       // fp32 -> bf16 RNE (no NaN inputs here)
  uint32_t u = __builtin_bit_cast(uint32_t, f);
  u += 0x7FFFu + ((u >> 16) & 1u);
  return (u16)(u >> 16);
}
DEV float bf2f(u16 s) { return __builtin_bit_cast(float, (uint32_t)s << 16); }

DEV void gl16(const void* g, void* l) {       // async global->LDS, 16B/lane
  __builtin_amdgcn_global_load_lds((const __attribute__((address_space(1))) void*)g,
                                   (__attribute__((address_space(3))) void*)l, 16, 0, 0);
}

// ---------------- fp32 -> bf16 convert ----------------
__global__ __launch_bounds__(256) void k_cvt(const float* __restrict__ in,
                                             u16* __restrict__ out, int n4) {
  int i = blockIdx.x * 256 + threadIdx.x;
  if (i >= n4) return;
  float4 v = reinterpret_cast<const float4*>(in)[i];
  uint2 o;
  o.x = (uint32_t)f2bf(v.x) | ((uint32_t)f2bf(v.y) << 16);
  o.y = (uint32_t)f2bf(v.z) | ((uint32_t)f2bf(v.w) << 16);
  reinterpret_cast<uint2*>(out)[i] = o;
}

// ---------------- NT GEMM: C[m,n] = alpha * sum_k A[m,k]*B[n,k] (+bias[n]) ---------
// A,B bf16 row-major K-contig. 128x128 tile, BK=32, 4 waves (2x2), 4x4 frags/wave.
template <bool OUT_BF16, bool BIAS>
__global__ __launch_bounds__(256, 2) void k_gemm_nt(
    const u16* __restrict__ A, const u16* __restrict__ B,
    void* __restrict__ Cv, const float* __restrict__ bias,
    int K, int lda, int ldb, int ldc,
    long long sA, long long sB, long long sC, float alpha) {
  const int bz = blockIdx.z;
  A += (long long)bz * sA;
  B += (long long)bz * sB;
  __shared__ alignas(16) u16 As[128 * 32];
  __shared__ alignas(16) u16 Bs[128 * 32];
  const int t    = threadIdx.x;
  const int lane = t & 63;
  const int wid  = t >> 6;
  const int wr   = wid >> 1, wc = wid & 1;
  const int l15  = lane & 15, l4 = lane >> 4;
  const int m0 = blockIdx.y * 128, n0 = blockIdx.x * 128;

  // staging: element el = t*8 (+2048 for 2nd issue); row = el>>5, col = el&31
  const int el0 = t * 8;
  const int r0 = el0 >> 5, c0 = el0 & 31;
  const u16* Ag = A + (long long)(m0 + r0) * lda + c0;
  const u16* Bg = B + (long long)(n0 + r0) * ldb + c0;
  const long long a64 = (long long)64 * lda;
  const long long b64 = (long long)64 * ldb;

  f32x4 acc[4][4];
#pragma unroll
  for (int m = 0; m < 4; ++m)
#pragma unroll
    for (int n = 0; n < 4; ++n) {
      f32x4 z = {0.f, 0.f, 0.f, 0.f};
      acc[m][n] = z;
    }

  for (int k0 = 0; k0 < K; k0 += 32) {
    gl16(Ag + k0,        &As[el0]);
    gl16(Ag + a64 + k0,  &As[el0 + 2048]);
    gl16(Bg + k0,        &Bs[el0]);
    gl16(Bg + b64 + k0,  &Bs[el0 + 2048]);
    __syncthreads();  // compiler emits vmcnt(0) drain before barrier
    bf16x8 af[4], bfr[4];
#pragma unroll
    for (int m = 0; m < 4; ++m)
      af[m] = *reinterpret_cast<const bf16x8*>(&As[(wr * 64 + m * 16 + l15) * 32 + l4 * 8]);
#pragma unroll
    for (int n = 0; n < 4; ++n)
      bfr[n] = *reinterpret_cast<const bf16x8*>(&Bs[(wc * 64 + n * 16 + l15) * 32 + l4 * 8]);
#pragma unroll
    for (int m = 0; m < 4; ++m)
#pragma unroll
      for (int n = 0; n < 4; ++n)
        acc[m][n] = __builtin_amdgcn_mfma_f32_16x16x32_bf16(af[m], bfr[n], acc[m][n], 0, 0, 0);
    __syncthreads();
  }

  const long long cbase = (long long)bz * sC;
#pragma unroll
  for (int m = 0; m < 4; ++m) {
#pragma unroll
    for (int n = 0; n < 4; ++n) {
      const int col = n0 + wc * 64 + n * 16 + l15;
      float bv = 0.f;
      if (BIAS) bv = bias[col];
#pragma unroll
      for (int r = 0; r < 4; ++r) {
        const int row = m0 + wr * 64 + m * 16 + l4 * 4 + r;
        float v = acc[m][n][r] * alpha + bv;
        if constexpr (OUT_BF16)
          ((u16*)Cv)[cbase + (long long)row * ldc + col] = f2bf(v);
        else
          ((float*)Cv)[cbase + (long long)row * ldc + col] = v;
      }
    }
  }
}

// ---------------- in-place row softmax over 2048 bf16 cols ----------------
__global__ __launch_bounds__(256) void k_softmax(u16* __restrict__ P) {
  const long long row = blockIdx.x;
  u16* p = P + row * 2048;
  const int t = threadIdx.x;
  us8 v = *reinterpret_cast<const us8*>(&p[t * 8]);
  float f[8];
#pragma unroll
  for (int j = 0; j < 8; ++j) f[j] = bf2f(v[j]);
  float m = f[0];
#pragma unroll
  for (int j = 1; j < 8; ++j) m = fmaxf(m, f[j]);
#pragma unroll
  for (int o = 32; o > 0; o >>= 1) m = fmaxf(m, __shfl_xor(m, o));
  __shared__ float redm[4], reds[4];
  if ((t & 63) == 0) redm[t >> 6] = m;
  __syncthreads();
  m = fmaxf(fmaxf(redm[0], redm[1]), fmaxf(redm[2], redm[3]));
  float s = 0.f;
#pragma unroll
  for (int j = 0; j < 8; ++j) {
    f[j] = __expf(f[j] - m);
    s += f[j];
  }
#pragma unroll
  for (int o = 32; o > 0; o >>= 1) s += __shfl_xor(s, o);
  if ((t & 63) == 0) reds[t >> 6] = s;
  __syncthreads();
  s = reds[0] + reds[1] + reds[2] + reds[3];
  const float inv = 1.0f / s;
  us8 o8;
#pragma unroll
  for (int j = 0; j < 8; ++j) o8[j] = f2bf(f[j] * inv);
  *reinterpret_cast<us8*>(&p[t * 8]) = o8;
}

// ---------------- tiled bf16 transpose: out[c][r] = in[r][c] ----------------
__global__ __launch_bounds__(256) void k_transpose(const u16* __restrict__ in,
                                                   u16* __restrict__ out,
                                                   int R, int C, long long stride) {
  __shared__ u16 tile[32][33];
  const long long base = (long long)blockIdx.z * stride;
  const int c0 = blockIdx.x * 32, r0 = blockIdx.y * 32;
  const int tx = threadIdx.x, ty = threadIdx.y;  // 32 x 8
#pragma unroll
  for (int i = 0; i < 32; i += 8)
    tile[ty + i][tx] = in[base + (long long)(r0 + ty + i) * C + (c0 + tx)];
  __syncthreads();
#pragma unroll
  for (int i = 0; i < 32; i += 8)
    out[base + (long long)(c0 + ty + i) * R + (r0 + tx)] = tile[tx][ty + i];
}

extern "C" void kernel_launch(void* const* d_in, const int* in_sizes, int n_in,
                              void* d_out, int out_size, void* d_ws, size_t ws_size,
                              hipStream_t stream) {
  (void)in_sizes; (void)n_in; (void)out_size;
  const float* x  = (const float*)d_in[0];
  const float* Wq = (const float*)d_in[1];
  const float* bq = (const float*)d_in[2];
  const float* Wk = (const float*)d_in[3];
  const float* bk = (const float*)d_in[4];
  const float* Wv = (const float*)d_in[5];
  const float* bv = (const float*)d_in[6];
  float* out = (float*)d_out;

  const int B = 4, S = 2048, D = 1024;
  const long long MX = (long long)B * S;  // 8192

  // ws layout (all bf16 u16 buffers)
  const long long need = MX * D * 2      // xb
                       + 3LL * D * D * 2 // W
                       + 3LL * MX * D * 2
                       + 2LL * B * S * S * 2
                       + 2LL * MX * D * 2;
  if ((long long)ws_size < need) return;  // insufficient scratch: leave output poisoned

  char* w = (char*)d_ws;
  u16* xb  = (u16*)w; w += MX * D * 2;
  u16* wqb = (u16*)w; w += (long long)D * D * 2;
  u16* wkb = (u16*)w; w += (long long)D * D * 2;
  u16* wvb = (u16*)w; w += (long long)D * D * 2;
  u16* qb  = (u16*)w; w += MX * D * 2;
  u16* kb  = (u16*)w; w += MX * D * 2;
  u16* vb  = (u16*)w; w += MX * D * 2;
  u16* P   = (u16*)w; w += (long long)B * S * S * 2;
  u16* PT  = (u16*)w; w += (long long)B * S * S * 2;
  u16* VT  = (u16*)w; w += MX * D * 2;
  u16* XT  = (u16*)w; w += MX * D * 2;

  dim3 blk(256);

  // converts
  {
    int n4 = (int)(MX * D / 4);
    k_cvt<<<dim3((n4 + 255) / 256), blk, 0, stream>>>(x, xb, n4);
    int w4 = D * D / 4;
    k_cvt<<<dim3((w4 + 255) / 256), blk, 0, stream>>>(Wq, wqb, w4);
    k_cvt<<<dim3((w4 + 255) / 256), blk, 0, stream>>>(Wk, wkb, w4);
    k_cvt<<<dim3((w4 + 255) / 256), blk, 0, stream>>>(Wv, wvb, w4);
  }

  // Q,K,V = X @ W^T + b   (M=8192, N=1024, K=1024)
  {
    dim3 g(D / 128, (int)(MX / 128), 1);
    k_gemm_nt<true, true><<<g, blk, 0, stream>>>(xb, wqb, qb, bq, D, D, D, D, 0, 0, 0, 1.0f);
    k_gemm_nt<true, true><<<g, blk, 0, stream>>>(xb, wkb, kb, bk, D, D, D, D, 0, 0, 0, 1.0f);
    k_gemm_nt<true, true><<<g, blk, 0, stream>>>(xb, wvb, vb, bv, D, D, D, D, 0, 0, 0, 1.0f);
  }

  // S = (Q @ K^T) * 1/sqrt(D), per batch (M=N=2048, K=1024), bf16 out into P
  {
    dim3 g(S / 128, S / 128, B);
    k_gemm_nt<true, false><<<g, blk, 0, stream>>>(qb, kb, P, nullptr, D, D, D, S,
        (long long)S * D, (long long)S * D, (long long)S * S, 0.03125f);
  }

  // softmax rows (in place): S -> attn (bf16)
  k_softmax<<<dim3((int)(B * S)), blk, 0, stream>>>(P);

  // transposes: P->PT, V->VT, X->XT (per batch)
  {
    dim3 tb(32, 8);
    k_transpose<<<dim3(S / 32, S / 32, B), tb, 0, stream>>>(P, PT, S, S, (long long)S * S);
    k_transpose<<<dim3(D / 32, S / 32, B), tb, 0, stream>>>(vb, VT, S, D, (long long)S * D);
    k_transpose<<<dim3(D / 32, S / 32, B), tb, 0, stream>>>(xb, XT, S, D, (long long)S * D);
  }

  // out1 = P @ V   == NT(P[2048,2048], VT[1024,2048]) -> fp32 [b][q][d]
  // out2 = P^T @ X == NT(PT[2048,2048], XT[1024,2048]) -> fp32 [b][k][d]
  {
    dim3 g(D / 128, S / 128, B);
    k_gemm_nt<false, false><<<g, blk, 0, stream>>>(P, VT, out, nullptr, S, S, S, D,
        (long long)S * S, (long long)S * D, (long long)S * D, 1.0f);
    k_gemm_nt<false, false><<<g, blk, 0, stream>>>(PT, XT, out + MX * D, nullptr, S, S, S, D,
        (long long)S * S, (long long)S * D, (long long)S * D, 1.0f);
  }
}

// Round 2
// 263.612 us; speedup vs baseline: 1.1665x; 1.1665x over previous
//
#include <hip/hip_runtime.h>
#include <hip/hip_bf16.h>
#include <stdint.h>

typedef unsigned short u16;
typedef u16   us8    __attribute__((ext_vector_type(8)));
typedef __bf16 bf16x8 __attribute__((ext_vector_type(8)));
typedef float f32x4  __attribute__((ext_vector_type(4)));

#define DEV static __device__ __forceinline__

DEV u16 f2bf(float f) {                       // fp32 -> bf16 RNE
  uint32_t u = __builtin_bit_cast(uint32_t, f);
  u += 0x7FFFu + ((u >> 16) & 1u);
  return (u16)(u >> 16);
}
DEV float bf2f(u16 s) { return __builtin_bit_cast(float, (uint32_t)s << 16); }

DEV void gl16(const void* g, void* l) {       // async global->LDS, 16B/lane
  __builtin_amdgcn_global_load_lds((const __attribute__((address_space(1))) void*)g,
                                   (__attribute__((address_space(3))) void*)l, 16, 0, 0);
}

// ---------------- fp32 -> bf16 convert ----------------
__global__ __launch_bounds__(256) void k_cvt(const float* __restrict__ in,
                                             u16* __restrict__ out, int n4) {
  int i = blockIdx.x * 256 + threadIdx.x;
  if (i >= n4) return;
  float4 v = reinterpret_cast<const float4*>(in)[i];
  uint2 o;
  o.x = (uint32_t)f2bf(v.x) | ((uint32_t)f2bf(v.y) << 16);
  o.y = (uint32_t)f2bf(v.z) | ((uint32_t)f2bf(v.w) << 16);
  reinterpret_cast<uint2*>(out)[i] = o;
}

// ---------------- concat 3 fp32 bias vectors [1024] -> [3072] ----------------
__global__ __launch_bounds__(256) void k_bias3(const float* __restrict__ a,
                                               const float* __restrict__ b,
                                               const float* __restrict__ c,
                                               float* __restrict__ o) {
  int i = blockIdx.x * 256 + threadIdx.x;
  if (i < 1024) o[i] = a[i];
  else if (i < 2048) o[i] = b[i - 1024];
  else if (i < 3072) o[i] = c[i - 2048];
}

// =================== 256x256-tile 8-phase NT GEMM ===================
// C[m,n] = alpha * sum_k A[m,k]*B[n,k] (+bias[n]).  A,B bf16 row-major K-contig.
// BM=BN=256, BK=64, 512 threads = 8 waves (2M x 4N), per-wave 128x64 output.
// LDS: As[2 slot][2 half][128x64], Bs same = 128 KiB. Half h = 128 contiguous
// global rows; phases per K-tile are C-quadrants (qm,qn) in order
// (0,0),(0,1),(1,0),(1,1) so A0 dies after ph1, B0 after ph2, A1/B1 after ph3.
// Stage schedule (derived + liveness-checked): ph0->A1(t+1), ph1->B1(t+1),
// ph2->A0(t+2), ph3->B0(t+2); boundary wait = vmcnt(4) ({A0,B0}(t+2) in
// flight), vmcnt(0) entering the last tile. Read-side XOR swizzle
// (16B-slot ^= row&7) with inverse-swizzled GLOBAL source (gl16 dest linear).
template <bool OUT_BF16, bool BIAS>
__global__ __launch_bounds__(512, 2) void k_gemm8(
    const u16* __restrict__ A, const u16* __restrict__ B,
    void* __restrict__ Cv, const float* __restrict__ bias,
    int K, int lda, int ldb, int ldc,
    long long sA, long long sB, long long sC, float alpha,
    int gx, int gy) {
  __shared__ alignas(16) u16 As[2][2][128 * 64];
  __shared__ alignas(16) u16 Bs[2][2][128 * 64];

  // T1: bijective XCD swizzle of a 1D grid (nwg % 8 == 0 for all launches)
  const int nwg = gridDim.x;
  int lin = blockIdx.x;
  lin = (lin & 7) * (nwg >> 3) + (lin >> 3);
  const int gxy = gx * gy;
  const int bz = lin / gxy;
  const int rem = lin - bz * gxy;
  const int by = rem / gx;
  const int bx = rem - by * gx;
  const int m0 = by * 256, n0 = bx * 256;

  A += (long long)bz * sA;
  B += (long long)bz * sB;

  const int t = threadIdx.x;
  const int lane = t & 63;
  const int wid = t >> 6;
  const int wm = wid >> 2;       // 0..1
  const int wn = wid & 3;        // 0..3
  const int l15 = lane & 15, l4 = lane >> 4;

  // staging geometry: thread t -> physical LDS bytes [t*16) and [t*16+8192)
  // physical row = t>>3 (+64), physical 16B-slot = t&7; logical slot = phys ^ (row&7)
  const int prow = t >> 3;
  const int scol = ((t & 7) ^ (prow & 7)) * 8;   // element col within K-tile (64 wide)
  const u16* Abase = A + (long long)(m0 + prow) * lda + scol;
  const u16* Bbase = B + (long long)(n0 + prow) * ldb + scol;
  const long long a64 = (long long)64 * lda, a128 = (long long)128 * lda;
  const long long b64 = (long long)64 * ldb, b128 = (long long)128 * ldb;
  u16* AsT = &As[0][0][0] + t * 8;
  u16* BsT = &Bs[0][0][0] + t * 8;

#define STG_A(h, kt) { const u16* s_ = Abase + (h) * a128 + (long long)(kt) * 64; \
    u16* d_ = AsT + (((kt) & 1) * 2 + (h)) * 8192; gl16(s_, d_); gl16(s_ + a64, d_ + 4096); }
#define STG_B(h, kt) { const u16* s_ = Bbase + (h) * b128 + (long long)(kt) * 64; \
    u16* d_ = BsT + (((kt) & 1) * 2 + (h)) * 8192; gl16(s_, d_); gl16(s_ + b64, d_ + 4096); }

  f32x4 acc[8][4];
#pragma unroll
  for (int i = 0; i < 8; ++i)
#pragma unroll
    for (int j = 0; j < 4; ++j) { f32x4 z = {0.f, 0.f, 0.f, 0.f}; acc[i][j] = z; }

  const int NT = K >> 6;   // K-tiles of 64 (>= 4, even)

  // prologue: tile0 fully + A0,B0 of tile1 (12 loads); wait tile0 landed
  STG_A(0, 0); STG_A(1, 0); STG_B(0, 0); STG_B(1, 0);
  STG_A(0, 1); STG_B(0, 1);
  asm volatile("s_waitcnt vmcnt(4)" ::: "memory");
  __builtin_amdgcn_s_barrier();

#define PHASE(p_, qm_, qn_, STAGES_, VMW_)                                     \
  {                                                                            \
    const u16* Ah = &As[p_][qm_][0];                                           \
    const u16* Bh = &Bs[p_][qn_][0];                                           \
    bf16x8 af[4][2], bf[2][2];                                                 \
    _Pragma("unroll") for (int f = 0; f < 4; ++f) {                            \
      const int row = wm * 64 + f * 16 + l15;                                  \
      _Pragma("unroll") for (int kk = 0; kk < 2; ++kk)                         \
        af[f][kk] = *(const bf16x8*)&Ah[row * 64 + (((kk * 4 + l4) ^ (l15 & 7)) * 8)]; \
    }                                                                          \
    _Pragma("unroll") for (int fn = 0; fn < 2; ++fn) {                         \
      const int row = wn * 32 + fn * 16 + l15;                                 \
      _Pragma("unroll") for (int kk = 0; kk < 2; ++kk)                         \
        bf[fn][kk] = *(const bf16x8*)&Bh[row * 64 + (((kk * 4 + l4) ^ (l15 & 7)) * 8)]; \
    }                                                                          \
    STAGES_;                                                                   \
    __builtin_amdgcn_s_barrier();                                              \
    asm volatile("s_waitcnt lgkmcnt(0)" ::: "memory");                         \
    __builtin_amdgcn_sched_barrier(0);                                         \
    __builtin_amdgcn_s_setprio(1);                                             \
    _Pragma("unroll") for (int f = 0; f < 4; ++f)                              \
      _Pragma("unroll") for (int fn = 0; fn < 2; ++fn) {                       \
        acc[qm_ * 4 + f][qn_ * 2 + fn] = __builtin_amdgcn_mfma_f32_16x16x32_bf16( \
            af[f][0], bf[fn][0], acc[qm_ * 4 + f][qn_ * 2 + fn], 0, 0, 0);     \
        acc[qm_ * 4 + f][qn_ * 2 + fn] = __builtin_amdgcn_mfma_f32_16x16x32_bf16( \
            af[f][1], bf[fn][1], acc[qm_ * 4 + f][qn_ * 2 + fn], 0, 0, 0);     \
      }                                                                        \
    __builtin_amdgcn_s_setprio(0);                                             \
    VMW_;                                                                      \
    __builtin_amdgcn_s_barrier();                                              \
  }

  for (int tt = 0; tt < NT; ++tt) {
    const int p = tt & 1;
    const bool s1 = (tt + 1 < NT);
    const bool s2 = (tt + 2 < NT);
    PHASE(p, 0, 0, if (s1) STG_A(1, tt + 1), );
    PHASE(p, 0, 1, if (s1) STG_B(1, tt + 1), );
    PHASE(p, 1, 0, if (s2) STG_A(0, tt + 2), );
    PHASE(p, 1, 1, if (s2) STG_B(0, tt + 2),
          if (s2) { asm volatile("s_waitcnt vmcnt(4)" ::: "memory"); }
          else    { asm volatile("s_waitcnt vmcnt(0)" ::: "memory"); });
  }
#undef PHASE
#undef STG_A
#undef STG_B

  // epilogue: C/D layout col=lane&15, row=(lane>>4)*4+reg (m89-verified)
  const long long cbase = (long long)bz * sC;
#pragma unroll
  for (int am = 0; am < 8; ++am) {
    const int qm = am >> 2, f = am & 3;
    const int grow0 = m0 + qm * 128 + wm * 64 + f * 16 + l4 * 4;
#pragma unroll
    for (int an = 0; an < 4; ++an) {
      const int qn = an >> 1, fn = an & 1;
      const int gcol = n0 + qn * 128 + wn * 32 + fn * 16 + l15;
      float bv = 0.f;
      if (BIAS) bv = bias[gcol];
#pragma unroll
      for (int r = 0; r < 4; ++r) {
        float v = acc[am][an][r] * alpha + bv;
        long long idx = cbase + (long long)(grow0 + r) * ldc + gcol;
        if constexpr (OUT_BF16) ((u16*)Cv)[idx] = f2bf(v);
        else                    ((float*)Cv)[idx] = v;
      }
    }
  }
}

// ---------------- in-place row softmax over 2048 bf16 cols ----------------
__global__ __launch_bounds__(256) void k_softmax(u16* __restrict__ P) {
  const long long row = blockIdx.x;
  u16* p = P + row * 2048;
  const int t = threadIdx.x;
  us8 v = *reinterpret_cast<const us8*>(&p[t * 8]);
  float f[8];
#pragma unroll
  for (int j = 0; j < 8; ++j) f[j] = bf2f(v[j]);
  float m = f[0];
#pragma unroll
  for (int j = 1; j < 8; ++j) m = fmaxf(m, f[j]);
#pragma unroll
  for (int o = 32; o > 0; o >>= 1) m = fmaxf(m, __shfl_xor(m, o));
  __shared__ float redm[4], reds[4];
  if ((t & 63) == 0) redm[t >> 6] = m;
  __syncthreads();
  m = fmaxf(fmaxf(redm[0], redm[1]), fmaxf(redm[2], redm[3]));
  float s = 0.f;
#pragma unroll
  for (int j = 0; j < 8; ++j) {
    f[j] = __expf(f[j] - m);
    s += f[j];
  }
#pragma unroll
  for (int o = 32; o > 0; o >>= 1) s += __shfl_xor(s, o);
  if ((t & 63) == 0) reds[t >> 6] = s;
  __syncthreads();
  s = reds[0] + reds[1] + reds[2] + reds[3];
  const float inv = 1.0f / s;
  us8 o8;
#pragma unroll
  for (int j = 0; j < 8; ++j) o8[j] = f2bf(f[j] * inv);
  *reinterpret_cast<us8*>(&p[t * 8]) = o8;
}

// ---- tiled bf16 transpose: out[c][r] = in[r][coff+c], per-batch strides ----
__global__ __launch_bounds__(256) void k_transpose(const u16* __restrict__ in,
                                                   u16* __restrict__ out,
                                                   int R, int ld_in, int coff,
                                                   long long sIn, long long sOut) {
  __shared__ u16 tile[32][33];
  const long long ibase = (long long)blockIdx.z * sIn;
  const long long obase = (long long)blockIdx.z * sOut;
  const int c0 = blockIdx.x * 32, r0 = blockIdx.y * 32;
  const int tx = threadIdx.x, ty = threadIdx.y;  // 32 x 8
#pragma unroll
  for (int i = 0; i < 32; i += 8)
    tile[ty + i][tx] = in[ibase + (long long)(r0 + ty + i) * ld_in + coff + c0 + tx];
  __syncthreads();
#pragma unroll
  for (int i = 0; i < 32; i += 8)
    out[obase + (long long)(c0 + ty + i) * R + (r0 + tx)] = tile[tx][ty + i];
}

extern "C" void kernel_launch(void* const* d_in, const int* in_sizes, int n_in,
                              void* d_out, int out_size, void* d_ws, size_t ws_size,
                              hipStream_t stream) {
  (void)in_sizes; (void)n_in; (void)out_size;
  const float* x  = (const float*)d_in[0];
  const float* Wq = (const float*)d_in[1];
  const float* bq = (const float*)d_in[2];
  const float* Wk = (const float*)d_in[3];
  const float* bk = (const float*)d_in[4];
  const float* Wv = (const float*)d_in[5];
  const float* bv = (const float*)d_in[6];
  float* out = (float*)d_out;

  const int B = 4, S = 2048, D = 1024;
  const long long MX = (long long)B * S;  // 8192

  const long long need = MX * D * 2              // xb
                       + 3LL * D * D * 2         // Wqkv
                       + 3072 * 4                // biasQKV
                       + MX * 3 * D * 2          // QKVb
                       + 2LL * B * S * S * 2     // P, PT (adjacent!)
                       + 2LL * MX * D * 2;       // VT, XT (adjacent!)
  if ((long long)ws_size < need) return;

  char* w = (char*)d_ws;
  u16*   xb   = (u16*)w;   w += MX * D * 2;
  u16*   Wqkv = (u16*)w;   w += 3LL * D * D * 2;
  float* bQKV = (float*)w; w += 3072 * 4;
  u16*   QKVb = (u16*)w;   w += MX * 3 * D * 2;
  u16*   P    = (u16*)w;   w += (long long)B * S * S * 2;
  u16*   PT   = (u16*)w;   w += (long long)B * S * S * 2;   // = P + 4*S*S
  u16*   VT   = (u16*)w;   w += MX * D * 2;
  u16*   XT   = (u16*)w;   w += MX * D * 2;                 // = VT + 4*D*S
  (void)PT; (void)XT;

  dim3 blk256(256), blk512(512);

  // converts + bias concat
  {
    int n4 = (int)(MX * D / 4);
    k_cvt<<<dim3((n4 + 255) / 256), blk256, 0, stream>>>(x, xb, n4);
    int w4 = D * D / 4;
    k_cvt<<<dim3((w4 + 255) / 256), blk256, 0, stream>>>(Wq, Wqkv, w4);
    k_cvt<<<dim3((w4 + 255) / 256), blk256, 0, stream>>>(Wk, Wqkv + (long long)D * D, w4);
    k_cvt<<<dim3((w4 + 255) / 256), blk256, 0, stream>>>(Wv, Wqkv + 2LL * D * D, w4);
    k_bias3<<<dim3(12), blk256, 0, stream>>>(bq, bk, bv, bQKV);
  }

  // QKV = X @ Wqkv^T + b : M=8192, N=3072, K=1024 -> QKVb [8192][3072]
  k_gemm8<true, true><<<dim3(12 * 32), blk512, 0, stream>>>(
      xb, Wqkv, QKVb, bQKV, D, D, D, 3 * D, 0, 0, 0, 1.0f, 12, 32);

  // S = (Q @ K^T)/32 per batch: M=N=2048, K=1024 -> P bf16
  k_gemm8<true, false><<<dim3(8 * 8 * 4), blk512, 0, stream>>>(
      QKVb, QKVb + D, P, nullptr, D, 3 * D, 3 * D, S,
      (long long)S * 3 * D, (long long)S * 3 * D, (long long)S * S, 0.03125f, 8, 8);

  // softmax rows in place
  k_softmax<<<dim3((int)(B * S)), blk256, 0, stream>>>(P);

  // transposes: P->PT ; V (QKVb cols 2048..3071) -> VT ; xb -> XT
  {
    dim3 tb(32, 8);
    k_transpose<<<dim3(64, 64, 4), tb, 0, stream>>>(P, PT, S, S, 0,
        (long long)S * S, (long long)S * S);
    k_transpose<<<dim3(32, 64, 4), tb, 0, stream>>>(QKVb, VT, S, 3 * D, 2 * D,
        (long long)S * 3 * D, (long long)D * S);
    k_transpose<<<dim3(32, 64, 4), tb, 0, stream>>>(xb, XT, S, D, 0,
        (long long)S * D, (long long)D * S);
  }

  // merged: z<4 -> out1[z] = P@V = NT(P, VT); z>=4 -> out2[z-4] = NT(PT, XT)
  // (PT = P + 4*S*S, XT = VT + 4*D*S, Cz = out + z*S*D  -- all uniform in z)
  k_gemm8<false, false><<<dim3(4 * 8 * 8), blk512, 0, stream>>>(
      P, VT, out, nullptr, S, S, S, D,
      (long long)S * S, (long long)D * S, (long long)S * D, 1.0f, 4, 8);
}

// Round 3
// 234.994 us; speedup vs baseline: 1.3086x; 1.1218x over previous
//
#include <hip/hip_runtime.h>
#include <hip/hip_bf16.h>
#include <stdint.h>

typedef unsigned short u16;
typedef u16   us8    __attribute__((ext_vector_type(8)));
typedef __bf16 bf16x8 __attribute__((ext_vector_type(8)));
typedef float f32x4  __attribute__((ext_vector_type(4)));

#define DEV static __device__ __forceinline__

DEV u16 f2bf(float f) {                       // fp32 -> bf16 RNE
  uint32_t u = __builtin_bit_cast(uint32_t, f);
  u += 0x7FFFu + ((u >> 16) & 1u);
  return (u16)(u >> 16);
}
DEV float bf2f(u16 s) { return __builtin_bit_cast(float, (uint32_t)s << 16); }

DEV void gl16(const void* g, void* l) {       // async global->LDS, 16B/lane
  __builtin_amdgcn_global_load_lds((const __attribute__((address_space(1))) void*)g,
                                   (__attribute__((address_space(3))) void*)l, 16, 0, 0);
}

// ------- fused fp32 -> bf16 convert for x, Wq, Wk, Wv (one dispatch) -------
// out = xb base; Wqkv buffer is laid out contiguously right after xb in ws.
__global__ __launch_bounds__(256) void k_cvt_all(
    const float* __restrict__ x, const float* __restrict__ wq,
    const float* __restrict__ wk, const float* __restrict__ wv,
    u16* __restrict__ out, int xn4, int wn4) {
  int i = blockIdx.x * 256 + threadIdx.x;
  const int total = xn4 + 3 * wn4;
  if (i >= total) return;
  const float* src;
  int idx;
  if (i < xn4) { src = x; idx = i; }
  else {
    int j = i - xn4;
    if (j < wn4) { src = wq; idx = j; }
    else if (j < 2 * wn4) { src = wk; idx = j - wn4; }
    else { src = wv; idx = j - 2 * wn4; }
  }
  float4 v = reinterpret_cast<const float4*>(src)[idx];
  uint2 o;
  o.x = (uint32_t)f2bf(v.x) | ((uint32_t)f2bf(v.y) << 16);
  o.y = (uint32_t)f2bf(v.z) | ((uint32_t)f2bf(v.w) << 16);
  reinterpret_cast<uint2*>(out)[i] = o;
}

// ---------------- concat 3 fp32 bias vectors [1024] -> [3072] ----------------
__global__ __launch_bounds__(256) void k_bias3(const float* __restrict__ a,
                                               const float* __restrict__ b,
                                               const float* __restrict__ c,
                                               float* __restrict__ o) {
  int i = blockIdx.x * 256 + threadIdx.x;
  if (i < 1024) o[i] = a[i];
  else if (i < 2048) o[i] = b[i - 1024];
  else if (i < 3072) o[i] = c[i - 2048];
}

// =================== 256x256-tile 8-phase NT GEMM ===================
// C[m,n] = alpha * sum_k A[m,k]*B[n,k] (+bias[n]).  A,B bf16 row-major K-contig.
// BM=BN=256, BK=64, 512 threads = 8 waves (2M x 4N), per-wave 128x64 output.
// LDS: As[2 slot][2 half][128x64], Bs same = 128 KiB.
// Phases per K-tile = C-quadrants (0,0),(0,1),(1,0),(1,1); stage schedule:
// ph0->A1(t+1), ph1->B1(t+1), ph2->A0(t+2), ph3->B0(t+2); boundary vmcnt(4)
// (vmcnt(0) entering last tile). ONE barrier per phase (closing): the opening
// barrier removed — phase-p stage never touches a half read in phase p, and
// BAR(p-1) already guarantees all phase-(p-1) reads completed (each wave only
// passes it after its own lgkmcnt(0)). Allows intra-phase wave skew so one
// wave's ds_reads overlap another's MFMA.
template <bool OUT_BF16, bool BIAS>
__global__ __launch_bounds__(512, 2) void k_gemm8(
    const u16* __restrict__ A, const u16* __restrict__ B,
    void* __restrict__ Cv, const float* __restrict__ bias,
    int K, int lda, int ldb, int ldc,
    long long sA, long long sB, long long sC, float alpha,
    int gx, int gy) {
  __shared__ alignas(16) u16 As[2][2][128 * 64];
  __shared__ alignas(16) u16 Bs[2][2][128 * 64];

  // T1: bijective XCD swizzle of a 1D grid (nwg % 8 == 0 for all launches)
  const int nwg = gridDim.x;
  int lin = blockIdx.x;
  lin = (lin & 7) * (nwg >> 3) + (lin >> 3);
  const int gxy = gx * gy;
  const int bz = lin / gxy;
  const int rem = lin - bz * gxy;
  const int by = rem / gx;
  const int bx = rem - by * gx;
  const int m0 = by * 256, n0 = bx * 256;

  A += (long long)bz * sA;
  B += (long long)bz * sB;

  const int t = threadIdx.x;
  const int lane = t & 63;
  const int wid = t >> 6;
  const int wm = wid >> 2;       // 0..1
  const int wn = wid & 3;        // 0..3
  const int l15 = lane & 15, l4 = lane >> 4;

  // staging: thread t -> physical LDS bytes [t*16) and [t*16+8192);
  // physical 16B-slot = t&7; source col pre-swizzled so READ-side XOR works.
  const int prow = t >> 3;
  const int scol = ((t & 7) ^ (prow & 7)) * 8;
  const u16* Abase = A + (long long)(m0 + prow) * lda + scol;
  const u16* Bbase = B + (long long)(n0 + prow) * ldb + scol;
  const long long a64 = (long long)64 * lda, a128 = (long long)128 * lda;
  const long long b64 = (long long)64 * ldb, b128 = (long long)128 * ldb;
  u16* AsT = &As[0][0][0] + t * 8;
  u16* BsT = &Bs[0][0][0] + t * 8;

#define STG_A(h, kt) { const u16* s_ = Abase + (h) * a128 + (long long)(kt) * 64; \
    u16* d_ = AsT + (((kt) & 1) * 2 + (h)) * 8192; gl16(s_, d_); gl16(s_ + a64, d_ + 4096); }
#define STG_B(h, kt) { const u16* s_ = Bbase + (h) * b128 + (long long)(kt) * 64; \
    u16* d_ = BsT + (((kt) & 1) * 2 + (h)) * 8192; gl16(s_, d_); gl16(s_ + b64, d_ + 4096); }

  f32x4 acc[8][4];
#pragma unroll
  for (int i = 0; i < 8; ++i)
#pragma unroll
    for (int j = 0; j < 4; ++j) { f32x4 z = {0.f, 0.f, 0.f, 0.f}; acc[i][j] = z; }

  const int NT = K >> 6;   // K-tiles of 64 (>= 4, even)

  // prologue: tile0 fully + A0,B0 of tile1 (12 loads); wait tile0 landed
  STG_A(0, 0); STG_A(1, 0); STG_B(0, 0); STG_B(1, 0);
  STG_A(0, 1); STG_B(0, 1);
  asm volatile("s_waitcnt vmcnt(4)" ::: "memory");
  __builtin_amdgcn_s_barrier();

#define PHASE(p_, qm_, qn_, STAGES_, VMW_)                                     \
  {                                                                            \
    const u16* Ah = &As[p_][qm_][0];                                           \
    const u16* Bh = &Bs[p_][qn_][0];                                           \
    bf16x8 af[4][2], bf[2][2];                                                 \
    _Pragma("unroll") for (int f = 0; f < 4; ++f) {                            \
      const int row = wm * 64 + f * 16 + l15;                                  \
      _Pragma("unroll") for (int kk = 0; kk < 2; ++kk)                         \
        af[f][kk] = *(const bf16x8*)&Ah[row * 64 + (((kk * 4 + l4) ^ (l15 & 7)) * 8)]; \
    }                                                                          \
    _Pragma("unroll") for (int fn = 0; fn < 2; ++fn) {                         \
      const int row = wn * 32 + fn * 16 + l15;                                 \
      _Pragma("unroll") for (int kk = 0; kk < 2; ++kk)                         \
        bf[fn][kk] = *(const bf16x8*)&Bh[row * 64 + (((kk * 4 + l4) ^ (l15 & 7)) * 8)]; \
    }                                                                          \
    STAGES_;                                                                   \
    asm volatile("s_waitcnt lgkmcnt(0)" ::: "memory");                         \
    __builtin_amdgcn_sched_barrier(0);                                         \
    __builtin_amdgcn_s_setprio(1);                                             \
    _Pragma("unroll") for (int f = 0; f < 4; ++f)                              \
      _Pragma("unroll") for (int fn = 0; fn < 2; ++fn) {                       \
        acc[qm_ * 4 + f][qn_ * 2 + fn] = __builtin_amdgcn_mfma_f32_16x16x32_bf16( \
            af[f][0], bf[fn][0], acc[qm_ * 4 + f][qn_ * 2 + fn], 0, 0, 0);     \
        acc[qm_ * 4 + f][qn_ * 2 + fn] = __builtin_amdgcn_mfma_f32_16x16x32_bf16( \
            af[f][1], bf[fn][1], acc[qm_ * 4 + f][qn_ * 2 + fn], 0, 0, 0);     \
      }                                                                        \
    __builtin_amdgcn_s_setprio(0);                                             \
    VMW_;                                                                      \
    __builtin_amdgcn_s_barrier();                                              \
  }

  for (int tt = 0; tt < NT; ++tt) {
    const int p = tt & 1;
    const bool s1 = (tt + 1 < NT);
    const bool s2 = (tt + 2 < NT);
    PHASE(p, 0, 0, if (s1) STG_A(1, tt + 1), );
    PHASE(p, 0, 1, if (s1) STG_B(1, tt + 1), );
    PHASE(p, 1, 0, if (s2) STG_A(0, tt + 2), );
    PHASE(p, 1, 1, if (s2) STG_B(0, tt + 2),
          if (s2) { asm volatile("s_waitcnt vmcnt(4)" ::: "memory"); }
          else    { asm volatile("s_waitcnt vmcnt(0)" ::: "memory"); });
  }
#undef PHASE
#undef STG_A
#undef STG_B

  // epilogue: C/D layout col=lane&15, row=(lane>>4)*4+reg (m89-verified)
  const long long cbase = (long long)bz * sC;
#pragma unroll
  for (int am = 0; am < 8; ++am) {
    const int qm = am >> 2, f = am & 3;
    const int grow0 = m0 + qm * 128 + wm * 64 + f * 16 + l4 * 4;
#pragma unroll
    for (int an = 0; an < 4; ++an) {
      const int qn = an >> 1, fn = an & 1;
      const int gcol = n0 + qn * 128 + wn * 32 + fn * 16 + l15;
      float bv = 0.f;
      if (BIAS) bv = bias[gcol];
#pragma unroll
      for (int r = 0; r < 4; ++r) {
        float v = acc[am][an][r] * alpha + bv;
        long long idx = cbase + (long long)(grow0 + r) * ldc + gcol;
        if constexpr (OUT_BF16) ((u16*)Cv)[idx] = f2bf(v);
        else                    ((float*)Cv)[idx] = v;
      }
    }
  }
}

// ---------------- in-place row softmax over 2048 bf16 cols ----------------
__global__ __launch_bounds__(256) void k_softmax(u16* __restrict__ P) {
  const long long row = blockIdx.x;
  u16* p = P + row * 2048;
  const int t = threadIdx.x;
  us8 v = *reinterpret_cast<const us8*>(&p[t * 8]);
  float f[8];
#pragma unroll
  for (int j = 0; j < 8; ++j) f[j] = bf2f(v[j]);
  float m = f[0];
#pragma unroll
  for (int j = 1; j < 8; ++j) m = fmaxf(m, f[j]);
#pragma unroll
  for (int o = 32; o > 0; o >>= 1) m = fmaxf(m, __shfl_xor(m, o));
  __shared__ float redm[4], reds[4];
  if ((t & 63) == 0) redm[t >> 6] = m;
  __syncthreads();
  m = fmaxf(fmaxf(redm[0], redm[1]), fmaxf(redm[2], redm[3]));
  float s = 0.f;
#pragma unroll
  for (int j = 0; j < 8; ++j) {
    f[j] = __expf(f[j] - m);
    s += f[j];
  }
#pragma unroll
  for (int o = 32; o > 0; o >>= 1) s += __shfl_xor(s, o);
  if ((t & 63) == 0) reds[t >> 6] = s;
  __syncthreads();
  s = reds[0] + reds[1] + reds[2] + reds[3];
  const float inv = 1.0f / s;
  us8 o8;
#pragma unroll
  for (int j = 0; j < 8; ++j) o8[j] = f2bf(f[j] * inv);
  *reinterpret_cast<us8*>(&p[t * 8]) = o8;
}

// ---- tiled bf16 transpose: out[c][r] = in[r][coff+c], per-batch strides ----
__global__ __launch_bounds__(256) void k_transpose(const u16* __restrict__ in,
                                                   u16* __restrict__ out,
                                                   int R, int ld_in, int coff,
                                                   long long sIn, long long sOut) {
  __shared__ u16 tile[32][33];
  const long long ibase = (long long)blockIdx.z * sIn;
  const long long obase = (long long)blockIdx.z * sOut;
  const int c0 = blockIdx.x * 32, r0 = blockIdx.y * 32;
  const int tx = threadIdx.x, ty = threadIdx.y;  // 32 x 8
#pragma unroll
  for (int i = 0; i < 32; i += 8)
    tile[ty + i][tx] = in[ibase + (long long)(r0 + ty + i) * ld_in + coff + c0 + tx];
  __syncthreads();
#pragma unroll
  for (int i = 0; i < 32; i += 8)
    out[obase + (long long)(c0 + ty + i) * R + (r0 + tx)] = tile[tx][ty + i];
}

extern "C" void kernel_launch(void* const* d_in, const int* in_sizes, int n_in,
                              void* d_out, int out_size, void* d_ws, size_t ws_size,
                              hipStream_t stream) {
  (void)in_sizes; (void)n_in; (void)out_size;
  const float* x  = (const float*)d_in[0];
  const float* Wq = (const float*)d_in[1];
  const float* bq = (const float*)d_in[2];
  const float* Wk = (const float*)d_in[3];
  const float* bk = (const float*)d_in[4];
  const float* Wv = (const float*)d_in[5];
  const float* bv = (const float*)d_in[6];
  float* out = (float*)d_out;

  const int B = 4, S = 2048, D = 1024;
  const long long MX = (long long)B * S;  // 8192

  const long long need = MX * D * 2              // xb
                       + 3LL * D * D * 2         // Wqkv (contiguous after xb!)
                       + 3072 * 4                // biasQKV
                       + MX * 3 * D * 2          // QKVb
                       + 2LL * B * S * S * 2     // P, PT (adjacent!)
                       + 2LL * MX * D * 2;       // VT, XT (adjacent!)
  if ((long long)ws_size < need) return;

  char* w = (char*)d_ws;
  u16*   xb   = (u16*)w;   w += MX * D * 2;
  u16*   Wqkv = (u16*)w;   w += 3LL * D * D * 2;  // = xb + MX*D
  float* bQKV = (float*)w; w += 3072 * 4;
  u16*   QKVb = (u16*)w;   w += MX * 3 * D * 2;
  u16*   P    = (u16*)w;   w += (long long)B * S * S * 2;
  u16*   PT   = (u16*)w;   w += (long long)B * S * S * 2;   // = P + 4*S*S
  u16*   VT   = (u16*)w;   w += MX * D * 2;
  u16*   XT   = (u16*)w;   w += MX * D * 2;                 // = VT + 4*D*S
  (void)Wqkv; (void)PT; (void)XT;

  dim3 blk256(256), blk512(512);

  // fused converts (xb and Wqkv contiguous -> single output pointer) + bias
  {
    int xn4 = (int)(MX * D / 4);          // 2097152
    int wn4 = D * D / 4;                  // 262144
    int tot = xn4 + 3 * wn4;
    k_cvt_all<<<dim3((tot + 255) / 256), blk256, 0, stream>>>(x, Wq, Wk, Wv, xb, xn4, wn4);
    k_bias3<<<dim3(12), blk256, 0, stream>>>(bq, bk, bv, bQKV);
  }

  // QKV = X @ Wqkv^T + b : M=8192, N=3072, K=1024 -> QKVb [8192][3072]
  k_gemm8<true, true><<<dim3(12 * 32), blk512, 0, stream>>>(
      xb, Wqkv, QKVb, bQKV, D, D, D, 3 * D, 0, 0, 0, 1.0f, 12, 32);

  // S = (Q @ K^T)/32 per batch: M=N=2048, K=1024 -> P bf16
  k_gemm8<true, false><<<dim3(8 * 8 * 4), blk512, 0, stream>>>(
      QKVb, QKVb + D, P, nullptr, D, 3 * D, 3 * D, S,
      (long long)S * 3 * D, (long long)S * 3 * D, (long long)S * S, 0.03125f, 8, 8);

  // softmax rows in place
  k_softmax<<<dim3((int)(B * S)), blk256, 0, stream>>>(P);

  // transposes: P->PT ; V (QKVb cols 2048..3071) -> VT ; xb -> XT
  {
    dim3 tb(32, 8);
    k_transpose<<<dim3(64, 64, 4), tb, 0, stream>>>(P, PT, S, S, 0,
        (long long)S * S, (long long)S * S);
    k_transpose<<<dim3(32, 64, 4), tb, 0, stream>>>(QKVb, VT, S, 3 * D, 2 * D,
        (long long)S * 3 * D, (long long)D * S);
    k_transpose<<<dim3(32, 64, 4), tb, 0, stream>>>(xb, XT, S, D, 0,
        (long long)S * D, (long long)D * S);
  }

  // merged: z<4 -> out1[z] = P@V = NT(P, VT); z>=4 -> out2[z-4] = NT(PT, XT)
  // (PT = P + 4*S*S, XT = VT + 4*D*S, Cz = out + z*S*D  -- all uniform in z)
  k_gemm8<false, false><<<dim3(4 * 8 * 8), blk512, 0, stream>>>(
      P, VT, out, nullptr, S, S, S, D,
      (long long)S * S, (long long)D * S, (long long)S * D, 1.0f, 4, 8);
}

// Round 4
// 223.312 us; speedup vs baseline: 1.3770x; 1.0523x over previous
//
#include <hip/hip_runtime.h>
#include <hip/hip_bf16.h>
#include <stdint.h>

typedef unsigned short u16;
typedef u16   us8    __attribute__((ext_vector_type(8)));
typedef __bf16 bf16x8 __attribute__((ext_vector_type(8)));
typedef float f32x4  __attribute__((ext_vector_type(4)));

#define DEV static __device__ __forceinline__

DEV u16 f2bf(float f) {                       // fp32 -> bf16 RNE
  uint32_t u = __builtin_bit_cast(uint32_t, f);
  u += 0x7FFFu + ((u >> 16) & 1u);
  return (u16)(u >> 16);
}
DEV float bf2f(u16 s) { return __builtin_bit_cast(float, (uint32_t)s << 16); }

DEV void gl16(const void* g, void* l) {       // async global->LDS, 16B/lane
  __builtin_amdgcn_global_load_lds((const __attribute__((address_space(1))) void*)g,
                                   (__attribute__((address_space(3))) void*)l, 16, 0, 0);
}

// ------- fused fp32 -> bf16 convert for x, Wq, Wk, Wv (one dispatch) -------
__global__ __launch_bounds__(256) void k_cvt_all(
    const float* __restrict__ x, const float* __restrict__ wq,
    const float* __restrict__ wk, const float* __restrict__ wv,
    u16* __restrict__ out, int xn4, int wn4) {
  int i = blockIdx.x * 256 + threadIdx.x;
  const int total = xn4 + 3 * wn4;
  if (i >= total) return;
  const float* src;
  int idx;
  if (i < xn4) { src = x; idx = i; }
  else {
    int j = i - xn4;
    if (j < wn4) { src = wq; idx = j; }
    else if (j < 2 * wn4) { src = wk; idx = j - wn4; }
    else { src = wv; idx = j - 2 * wn4; }
  }
  float4 v = reinterpret_cast<const float4*>(src)[idx];
  uint2 o;
  o.x = (uint32_t)f2bf(v.x) | ((uint32_t)f2bf(v.y) << 16);
  o.y = (uint32_t)f2bf(v.z) | ((uint32_t)f2bf(v.w) << 16);
  reinterpret_cast<uint2*>(out)[i] = o;
}

// ---------------- concat 3 fp32 bias vectors [1024] -> [3072] ----------------
__global__ __launch_bounds__(256) void k_bias3(const float* __restrict__ a,
                                               const float* __restrict__ b,
                                               const float* __restrict__ c,
                                               float* __restrict__ o) {
  int i = blockIdx.x * 256 + threadIdx.x;
  if (i < 1024) o[i] = a[i];
  else if (i < 2048) o[i] = b[i - 1024];
  else if (i < 3072) o[i] = c[i - 2048];
}

// =================== 256x256-tile 2-phase-per-K-tile NT GEMM ===================
// C[m,n] = alpha * sum_k A[m,k]*B[n,k] (+bias[n]).  A,B bf16 row-major K-contig.
// BM=BN=256, BK=64, 512 threads = 8 waves (2M x 4N), per-wave 128x64 output.
// LDS: As[2 slot][2 half][128x64], Bs same = 128 KiB.
// Phases per K-tile split by A-HALF (register-reuse restructure):
//   PH0 (qm=0): read af0 (8 b128) + ALL bf (8 b128), 32 MFMA; stage A1,B1(t+1).
//   PH1 (qm=1): read af1 (8), HOLD bf in regs, 32 MFMA; stage A0,B0(t+2).
// 24 ds_read/tile/wave (vs 48 quadrant-phased) -> LDS 2312 cyc/tile/CU < MFMA
// 2483 cyc -> MFMA-dominant. Liveness: PH0 stages slot p^1 (tile-t reads are
// slot p); PH1 stages A0/B0 slot p whose tile-t reads completed at PH0's lgkm,
// fenced by PH0's closing barrier (max skew 1 phase). Boundary in-flight = 12
// loads, first 8 = tile t+1 -> vmcnt(4); vmcnt(0) entering last tile.
template <bool OUT_BF16, bool BIAS>
__global__ __launch_bounds__(512, 2) void k_gemm8(
    const u16* __restrict__ A, const u16* __restrict__ B,
    void* __restrict__ Cv, const float* __restrict__ bias,
    int K, int lda, int ldb, int ldc,
    long long sA, long long sB, long long sC, float alpha,
    int gx, int gy) {
  __shared__ alignas(16) u16 As[2][2][128 * 64];
  __shared__ alignas(16) u16 Bs[2][2][128 * 64];

  // T1: bijective XCD swizzle of a 1D grid (nwg % 8 == 0 for all launches)
  const int nwg = gridDim.x;
  int lin = blockIdx.x;
  lin = (lin & 7) * (nwg >> 3) + (lin >> 3);
  const int gxy = gx * gy;
  const int bz = lin / gxy;
  const int rem = lin - bz * gxy;
  const int by = rem / gx;
  const int bx = rem - by * gx;
  const int m0 = by * 256, n0 = bx * 256;

  A += (long long)bz * sA;
  B += (long long)bz * sB;

  const int t = threadIdx.x;
  const int lane = t & 63;
  const int wid = t >> 6;
  const int wm = wid >> 2;       // 0..1
  const int wn = wid & 3;        // 0..3
  const int l15 = lane & 15, l4 = lane >> 4;

  // staging: thread t -> physical LDS bytes [t*16) and [t*16+8192);
  // physical 16B-slot = t&7; source col pre-swizzled so READ-side XOR works.
  const int prow = t >> 3;
  const int scol = ((t & 7) ^ (prow & 7)) * 8;
  const u16* Abase = A + (long long)(m0 + prow) * lda + scol;
  const u16* Bbase = B + (long long)(n0 + prow) * ldb + scol;
  const long long a64 = (long long)64 * lda, a128 = (long long)128 * lda;
  const long long b64 = (long long)64 * ldb, b128 = (long long)128 * ldb;
  u16* AsT = &As[0][0][0] + t * 8;
  u16* BsT = &Bs[0][0][0] + t * 8;

#define STG_A(h, kt) { const u16* s_ = Abase + (h) * a128 + (long long)(kt) * 64; \
    u16* d_ = AsT + (((kt) & 1) * 2 + (h)) * 8192; gl16(s_, d_); gl16(s_ + a64, d_ + 4096); }
#define STG_B(h, kt) { const u16* s_ = Bbase + (h) * b128 + (long long)(kt) * 64; \
    u16* d_ = BsT + (((kt) & 1) * 2 + (h)) * 8192; gl16(s_, d_); gl16(s_ + b64, d_ + 4096); }

  f32x4 acc[8][4];
#pragma unroll
  for (int i = 0; i < 8; ++i)
#pragma unroll
    for (int j = 0; j < 4; ++j) { f32x4 z = {0.f, 0.f, 0.f, 0.f}; acc[i][j] = z; }

  const int NT = K >> 6;   // K-tiles of 64 (>= 3 required; ours are 16)

  // prologue: tile0 fully + A0,B0 of tile1 (12 loads); wait tile0 landed
  STG_A(0, 0); STG_A(1, 0); STG_B(0, 0); STG_B(1, 0);
  STG_A(0, 1); STG_B(0, 1);
  asm volatile("s_waitcnt vmcnt(4)" ::: "memory");
  __builtin_amdgcn_s_barrier();

  for (int tt = 0; tt < NT; ++tt) {
    const int p = tt & 1;
    const bool s1 = (tt + 1 < NT);
    const bool s2 = (tt + 2 < NT);
    bf16x8 bfr[4][2];   // all B fragments: fn -> (qn=fn>>1, sub=fn&1); live both phases

    // ---------------- PH0: qm = 0 ----------------
    {
      const u16* Ah = &As[p][0][0];
      bf16x8 af[4][2];
#pragma unroll
      for (int f = 0; f < 4; ++f) {
        const int ro = (wm * 64 + f * 16 + l15) * 64;
#pragma unroll
        for (int kk = 0; kk < 2; ++kk)
          af[f][kk] = *(const bf16x8*)&Ah[ro + (((kk * 4 + l4) ^ (l15 & 7)) * 8)];
      }
#pragma unroll
      for (int fn = 0; fn < 4; ++fn) {
        const u16* Bh = &Bs[p][fn >> 1][0];
        const int ro = (wn * 32 + (fn & 1) * 16 + l15) * 64;
#pragma unroll
        for (int kk = 0; kk < 2; ++kk)
          bfr[fn][kk] = *(const bf16x8*)&Bh[ro + (((kk * 4 + l4) ^ (l15 & 7)) * 8)];
      }
      if (s1) { STG_A(1, tt + 1); STG_B(1, tt + 1); }
      asm volatile("s_waitcnt lgkmcnt(0)" ::: "memory");
      __builtin_amdgcn_sched_barrier(0);
      __builtin_amdgcn_s_setprio(1);
#pragma unroll
      for (int f = 0; f < 4; ++f)
#pragma unroll
        for (int fn = 0; fn < 4; ++fn) {
          acc[f][fn] = __builtin_amdgcn_mfma_f32_16x16x32_bf16(af[f][0], bfr[fn][0], acc[f][fn], 0, 0, 0);
          acc[f][fn] = __builtin_amdgcn_mfma_f32_16x16x32_bf16(af[f][1], bfr[fn][1], acc[f][fn], 0, 0, 0);
        }
      __builtin_amdgcn_s_setprio(0);
      __builtin_amdgcn_s_barrier();
    }

    // ---------------- PH1: qm = 1 (bfr held in registers) ----------------
    {
      const u16* Ah = &As[p][1][0];
      bf16x8 af[4][2];
#pragma unroll
      for (int f = 0; f < 4; ++f) {
        const int ro = (wm * 64 + f * 16 + l15) * 64;
#pragma unroll
        for (int kk = 0; kk < 2; ++kk)
          af[f][kk] = *(const bf16x8*)&Ah[ro + (((kk * 4 + l4) ^ (l15 & 7)) * 8)];
      }
      if (s2) { STG_A(0, tt + 2); STG_B(0, tt + 2); }
      asm volatile("s_waitcnt lgkmcnt(0)" ::: "memory");
      __builtin_amdgcn_sched_barrier(0);
      __builtin_amdgcn_s_setprio(1);
#pragma unroll
      for (int f = 0; f < 4; ++f)
#pragma unroll
        for (int fn = 0; fn < 4; ++fn) {
          acc[4 + f][fn] = __builtin_amdgcn_mfma_f32_16x16x32_bf16(af[f][0], bfr[fn][0], acc[4 + f][fn], 0, 0, 0);
          acc[4 + f][fn] = __builtin_amdgcn_mfma_f32_16x16x32_bf16(af[f][1], bfr[fn][1], acc[4 + f][fn], 0, 0, 0);
        }
      __builtin_amdgcn_s_setprio(0);
      if (s2) { asm volatile("s_waitcnt vmcnt(4)" ::: "memory"); }
      else    { asm volatile("s_waitcnt vmcnt(0)" ::: "memory"); }
      __builtin_amdgcn_s_barrier();
    }
  }
#undef STG_A
#undef STG_B

  // epilogue: C/D layout col=lane&15, row=(lane>>4)*4+reg (m89-verified)
  const long long cbase = (long long)bz * sC;
#pragma unroll
  for (int am = 0; am < 8; ++am) {
    const int qm = am >> 2, f = am & 3;
    const int grow0 = m0 + qm * 128 + wm * 64 + f * 16 + l4 * 4;
#pragma unroll
    for (int an = 0; an < 4; ++an) {
      const int gcol = n0 + (an >> 1) * 128 + wn * 32 + (an & 1) * 16 + l15;
      float bv = 0.f;
      if (BIAS) bv = bias[gcol];
#pragma unroll
      for (int r = 0; r < 4; ++r) {
        float v = acc[am][an][r] * alpha + bv;
        long long idx = cbase + (long long)(grow0 + r) * ldc + gcol;
        if constexpr (OUT_BF16) ((u16*)Cv)[idx] = f2bf(v);
        else                    ((float*)Cv)[idx] = v;
      }
    }
  }
}

// ---------------- in-place row softmax over 2048 bf16 cols ----------------
__global__ __launch_bounds__(256) void k_softmax(u16* __restrict__ P) {
  const long long row = blockIdx.x;
  u16* p = P + row * 2048;
  const int t = threadIdx.x;
  us8 v = *reinterpret_cast<const us8*>(&p[t * 8]);
  float f[8];
#pragma unroll
  for (int j = 0; j < 8; ++j) f[j] = bf2f(v[j]);
  float m = f[0];
#pragma unroll
  for (int j = 1; j < 8; ++j) m = fmaxf(m, f[j]);
#pragma unroll
  for (int o = 32; o > 0; o >>= 1) m = fmaxf(m, __shfl_xor(m, o));
  __shared__ float redm[4], reds[4];
  if ((t & 63) == 0) redm[t >> 6] = m;
  __syncthreads();
  m = fmaxf(fmaxf(redm[0], redm[1]), fmaxf(redm[2], redm[3]));
  float s = 0.f;
#pragma unroll
  for (int j = 0; j < 8; ++j) {
    f[j] = __expf(f[j] - m);
    s += f[j];
  }
#pragma unroll
  for (int o = 32; o > 0; o >>= 1) s += __shfl_xor(s, o);
  if ((t & 63) == 0) reds[t >> 6] = s;
  __syncthreads();
  s = reds[0] + reds[1] + reds[2] + reds[3];
  const float inv = 1.0f / s;
  us8 o8;
#pragma unroll
  for (int j = 0; j < 8; ++j) o8[j] = f2bf(f[j] * inv);
  *reinterpret_cast<us8*>(&p[t * 8]) = o8;
}

// ---- tiled bf16 transpose: out[c][r] = in[r][coff+c], per-batch strides ----
__global__ __launch_bounds__(256) void k_transpose(const u16* __restrict__ in,
                                                   u16* __restrict__ out,
                                                   int R, int ld_in, int coff,
                                                   long long sIn, long long sOut) {
  __shared__ u16 tile[32][33];
  const long long ibase = (long long)blockIdx.z * sIn;
  const long long obase = (long long)blockIdx.z * sOut;
  const int c0 = blockIdx.x * 32, r0 = blockIdx.y * 32;
  const int tx = threadIdx.x, ty = threadIdx.y;  // 32 x 8
#pragma unroll
  for (int i = 0; i < 32; i += 8)
    tile[ty + i][tx] = in[ibase + (long long)(r0 + ty + i) * ld_in + coff + c0 + tx];
  __syncthreads();
#pragma unroll
  for (int i = 0; i < 32; i += 8)
    out[obase + (long long)(c0 + ty + i) * R + (r0 + tx)] = tile[tx][ty + i];
}

extern "C" void kernel_launch(void* const* d_in, const int* in_sizes, int n_in,
                              void* d_out, int out_size, void* d_ws, size_t ws_size,
                              hipStream_t stream) {
  (void)in_sizes; (void)n_in; (void)out_size;
  const float* x  = (const float*)d_in[0];
  const float* Wq = (const float*)d_in[1];
  const float* bq = (const float*)d_in[2];
  const float* Wk = (const float*)d_in[3];
  const float* bk = (const float*)d_in[4];
  const float* Wv = (const float*)d_in[5];
  const float* bv = (const float*)d_in[6];
  float* out = (float*)d_out;

  const int B = 4, S = 2048, D = 1024;
  const long long MX = (long long)B * S;  // 8192

  const long long need = MX * D * 2              // xb
                       + 3LL * D * D * 2         // Wqkv (contiguous after xb!)
                       + 3072 * 4                // biasQKV
                       + MX * 3 * D * 2          // QKVb
                       + 2LL * B * S * S * 2     // P, PT (adjacent!)
                       + 2LL * MX * D * 2;       // VT, XT (adjacent!)
  if ((long long)ws_size < need) return;

  char* w = (char*)d_ws;
  u16*   xb   = (u16*)w;   w += MX * D * 2;
  u16*   Wqkv = (u16*)w;   w += 3LL * D * D * 2;  // = xb + MX*D
  float* bQKV = (float*)w; w += 3072 * 4;
  u16*   QKVb = (u16*)w;   w += MX * 3 * D * 2;
  u16*   P    = (u16*)w;   w += (long long)B * S * S * 2;
  u16*   PT   = (u16*)w;   w += (long long)B * S * S * 2;   // = P + 4*S*S
  u16*   VT   = (u16*)w;   w += MX * D * 2;
  u16*   XT   = (u16*)w;   w += MX * D * 2;                 // = VT + 4*D*S
  (void)Wqkv; (void)PT; (void)XT;

  dim3 blk256(256), blk512(512);

  // fused converts (xb and Wqkv contiguous -> single output pointer) + bias
  {
    int xn4 = (int)(MX * D / 4);          // 2097152
    int wn4 = D * D / 4;                  // 262144
    int tot = xn4 + 3 * wn4;
    k_cvt_all<<<dim3((tot + 255) / 256), blk256, 0, stream>>>(x, Wq, Wk, Wv, xb, xn4, wn4);
    k_bias3<<<dim3(12), blk256, 0, stream>>>(bq, bk, bv, bQKV);
  }

  // QKV = X @ Wqkv^T + b : M=8192, N=3072, K=1024 -> QKVb [8192][3072]
  k_gemm8<true, true><<<dim3(12 * 32), blk512, 0, stream>>>(
      xb, Wqkv, QKVb, bQKV, D, D, D, 3 * D, 0, 0, 0, 1.0f, 12, 32);

  // S = (Q @ K^T)/32 per batch: M=N=2048, K=1024 -> P bf16
  k_gemm8<true, false><<<dim3(8 * 8 * 4), blk512, 0, stream>>>(
      QKVb, QKVb + D, P, nullptr, D, 3 * D, 3 * D, S,
      (long long)S * 3 * D, (long long)S * 3 * D, (long long)S * S, 0.03125f, 8, 8);

  // softmax rows in place
  k_softmax<<<dim3((int)(B * S)), blk256, 0, stream>>>(P);

  // transposes: P->PT ; V (QKVb cols 2048..3071) -> VT ; xb -> XT
  {
    dim3 tb(32, 8);
    k_transpose<<<dim3(64, 64, 4), tb, 0, stream>>>(P, PT, S, S, 0,
        (long long)S * S, (long long)S * S);
    k_transpose<<<dim3(32, 64, 4), tb, 0, stream>>>(QKVb, VT, S, 3 * D, 2 * D,
        (long long)S * 3 * D, (long long)D * S);
    k_transpose<<<dim3(32, 64, 4), tb, 0, stream>>>(xb, XT, S, D, 0,
        (long long)S * D, (long long)D * S);
  }

  // merged: z<4 -> out1[z] = P@V = NT(P, VT); z>=4 -> out2[z-4] = NT(PT, XT)
  // (PT = P + 4*S*S, XT = VT + 4*D*S, Cz = out + z*S*D  -- all uniform in z)
  k_gemm8<false, false><<<dim3(4 * 8 * 8), blk512, 0, stream>>>(
      P, VT, out, nullptr, S, S, S, D,
      (long long)S * S, (long long)D * S, (long long)S * D, 1.0f, 4, 8);
}

// Round 5
// 222.905 us; speedup vs baseline: 1.3795x; 1.0018x over previous
//
#include <hip/hip_runtime.h>
#include <hip/hip_bf16.h>
#include <stdint.h>

typedef unsigned short u16;
typedef u16   us8    __attribute__((ext_vector_type(8)));
typedef __bf16 bf16x8 __attribute__((ext_vector_type(8)));
typedef float f32x4  __attribute__((ext_vector_type(4)));

#define DEV static __device__ __forceinline__

DEV u16 f2bf(float f) {                       // fp32 -> bf16 RNE
  uint32_t u = __builtin_bit_cast(uint32_t, f);
  u += 0x7FFFu + ((u >> 16) & 1u);
  return (u16)(u >> 16);
}
DEV float bf2f(u16 s) { return __builtin_bit_cast(float, (uint32_t)s << 16); }

DEV void gl16(const void* g, void* l) {       // async global->LDS, 16B/lane
  __builtin_amdgcn_global_load_lds((const __attribute__((address_space(1))) void*)g,
                                   (__attribute__((address_space(3))) void*)l, 16, 0, 0);
}

// ------- fused fp32 -> bf16 convert for x, Wq, Wk, Wv (one dispatch) -------
__global__ __launch_bounds__(256) void k_cvt_all(
    const float* __restrict__ x, const float* __restrict__ wq,
    const float* __restrict__ wk, const float* __restrict__ wv,
    u16* __restrict__ out, int xn4, int wn4) {
  int i = blockIdx.x * 256 + threadIdx.x;
  const int total = xn4 + 3 * wn4;
  if (i >= total) return;
  const float* src;
  int idx;
  if (i < xn4) { src = x; idx = i; }
  else {
    int j = i - xn4;
    if (j < wn4) { src = wq; idx = j; }
    else if (j < 2 * wn4) { src = wk; idx = j - wn4; }
    else { src = wv; idx = j - 2 * wn4; }
  }
  float4 v = reinterpret_cast<const float4*>(src)[idx];
  uint2 o;
  o.x = (uint32_t)f2bf(v.x) | ((uint32_t)f2bf(v.y) << 16);
  o.y = (uint32_t)f2bf(v.z) | ((uint32_t)f2bf(v.w) << 16);
  reinterpret_cast<uint2*>(out)[i] = o;
}

// ---------------- concat 3 fp32 bias vectors [1024] -> [3072] ----------------
__global__ __launch_bounds__(256) void k_bias3(const float* __restrict__ a,
                                               const float* __restrict__ b,
                                               const float* __restrict__ c,
                                               float* __restrict__ o) {
  int i = blockIdx.x * 256 + threadIdx.x;
  if (i < 1024) o[i] = a[i];
  else if (i < 2048) o[i] = b[i - 1024];
  else if (i < 3072) o[i] = c[i - 2048];
}

// =================== 256x256-tile 2-phase NT GEMM, counted-lgkm interleave ===
// C[m,n] = alpha * sum_k A[m,k]*B[n,k] (+bias[n]).  A,B bf16 row-major K-contig.
// BM=BN=256, BK=64, 512 threads = 8 waves (2M x 4N), per-wave 128x64 output.
// LDS: As[2 slot][2 half][128x64], Bs same = 128 KiB.
// R4 skeleton (2 phases/K-tile split by A-half, stage PH0->A1B1(t+1),
// PH1->A0B0(t+2), boundary vmcnt(4), one closing barrier per phase) PLUS
// counted-lgkm read/MFMA interleave: reads issued in sched_barrier(0)-fenced
// clusters; MFMA clusters gated by lgkmcnt(12/6/4/2) so LDS latency hides
// under MFMA instead of a full lgkmcnt(0) drain. PH1's f0 A-frag prefetched
// in PH0 (same LDS half, stable all tile).
#define SB0 __builtin_amdgcn_sched_barrier(0)
#define LGKM(N) do { asm volatile("s_waitcnt lgkmcnt(" #N ")" ::: "memory"); \
                     __builtin_amdgcn_sched_barrier(0); } while (0)

template <bool OUT_BF16, bool BIAS>
__global__ __launch_bounds__(512, 2) void k_gemm8(
    const u16* __restrict__ A, const u16* __restrict__ B,
    void* __restrict__ Cv, const float* __restrict__ bias,
    int K, int lda, int ldb, int ldc,
    long long sA, long long sB, long long sC, float alpha,
    int gx, int gy) {
  __shared__ alignas(16) u16 As[2][2][128 * 64];
  __shared__ alignas(16) u16 Bs[2][2][128 * 64];

  // T1: bijective XCD swizzle of a 1D grid (nwg % 8 == 0 for all launches)
  const int nwg = gridDim.x;
  int lin = blockIdx.x;
  lin = (lin & 7) * (nwg >> 3) + (lin >> 3);
  const int gxy = gx * gy;
  const int bz = lin / gxy;
  const int rem = lin - bz * gxy;
  const int by = rem / gx;
  const int bx = rem - by * gx;
  const int m0 = by * 256, n0 = bx * 256;

  A += (long long)bz * sA;
  B += (long long)bz * sB;

  const int t = threadIdx.x;
  const int lane = t & 63;
  const int wid = t >> 6;
  const int wm = wid >> 2;       // 0..1
  const int wn = wid & 3;        // 0..3
  const int l15 = lane & 15, l4 = lane >> 4;

  // staging: thread t -> physical LDS bytes [t*16) and [t*16+8192);
  // physical 16B-slot = t&7; source col pre-swizzled so READ-side XOR works.
  const int prow = t >> 3;
  const int scol = ((t & 7) ^ (prow & 7)) * 8;
  const u16* Abase = A + (long long)(m0 + prow) * lda + scol;
  const u16* Bbase = B + (long long)(n0 + prow) * ldb + scol;
  const long long a64 = (long long)64 * lda, a128 = (long long)128 * lda;
  const long long b64 = (long long)64 * ldb, b128 = (long long)128 * ldb;
  u16* AsT = &As[0][0][0] + t * 8;
  u16* BsT = &Bs[0][0][0] + t * 8;

#define STG_A(h, kt) { const u16* s_ = Abase + (h) * a128 + (long long)(kt) * 64; \
    u16* d_ = AsT + (((kt) & 1) * 2 + (h)) * 8192; gl16(s_, d_); gl16(s_ + a64, d_ + 4096); }
#define STG_B(h, kt) { const u16* s_ = Bbase + (h) * b128 + (long long)(kt) * 64; \
    u16* d_ = BsT + (((kt) & 1) * 2 + (h)) * 8192; gl16(s_, d_); gl16(s_ + b64, d_ + 4096); }

  // read-side addressing (swizzled)
  const int aro = wm * 64 + l15;          // + f*16
  const int bro = wn * 32 + l15;          // + (fn&1)*16
  const int cs0 = ((l4) ^ (l15 & 7)) * 8;
  const int cs1 = ((4 + l4) ^ (l15 & 7)) * 8;
#define LD(base, row, cs) (*(const bf16x8*)&(base)[(row) * 64 + (cs)])

  f32x4 acc[8][4];
#pragma unroll
  for (int i = 0; i < 8; ++i)
#pragma unroll
    for (int j = 0; j < 4; ++j) { f32x4 z = {0.f, 0.f, 0.f, 0.f}; acc[i][j] = z; }

  const int NT = K >> 6;   // K-tiles of 64 (>= 3 required; ours are 16/32)

  // prologue: tile0 fully + A0,B0 of tile1 (12 loads); wait tile0 landed
  STG_A(0, 0); STG_A(1, 0); STG_B(0, 0); STG_B(1, 0);
  STG_A(0, 1); STG_B(0, 1);
  asm volatile("s_waitcnt vmcnt(4)" ::: "memory");
  __builtin_amdgcn_s_barrier();

#define MM0(f_, fn_)                                                            \
  acc[f_][fn_] = __builtin_amdgcn_mfma_f32_16x16x32_bf16(af[f_][0], bfr[fn_][0], acc[f_][fn_], 0, 0, 0); \
  acc[f_][fn_] = __builtin_amdgcn_mfma_f32_16x16x32_bf16(af[f_][1], bfr[fn_][1], acc[f_][fn_], 0, 0, 0)
#define MM1P(fn_)                                                               \
  acc[4][fn_] = __builtin_amdgcn_mfma_f32_16x16x32_bf16(a1[0], bfr[fn_][0], acc[4][fn_], 0, 0, 0); \
  acc[4][fn_] = __builtin_amdgcn_mfma_f32_16x16x32_bf16(a1[1], bfr[fn_][1], acc[4][fn_], 0, 0, 0)
#define MM1(f_, fn_)                                                            \
  acc[4 + (f_)][fn_] = __builtin_amdgcn_mfma_f32_16x16x32_bf16(af1[(f_) - 1][0], bfr[fn_][0], acc[4 + (f_)][fn_], 0, 0, 0); \
  acc[4 + (f_)][fn_] = __builtin_amdgcn_mfma_f32_16x16x32_bf16(af1[(f_) - 1][1], bfr[fn_][1], acc[4 + (f_)][fn_], 0, 0, 0)

  for (int tt = 0; tt < NT; ++tt) {
    const int p = tt & 1;
    const bool s1 = (tt + 1 < NT);
    const bool s2 = (tt + 2 < NT);
    bf16x8 bfr[4][2];   // all B fragments, live both phases
    bf16x8 a1[2];       // PH1 f0 A-frag, prefetched in PH0

    // ---------------- PH0: qm = 0 ----------------
    {
      const u16* Ah  = &As[p][0][0];
      const u16* Ah1 = &As[p][1][0];
      const u16* Bh0 = &Bs[p][0][0];
      const u16* Bh1 = &Bs[p][1][0];
      bf16x8 af[4][2];
      // C1: bfr0, bfr1, af0  (6 reads)
      bfr[0][0] = LD(Bh0, bro, cs0);      bfr[0][1] = LD(Bh0, bro, cs1);
      bfr[1][0] = LD(Bh0, bro + 16, cs0); bfr[1][1] = LD(Bh0, bro + 16, cs1);
      af[0][0]  = LD(Ah, aro, cs0);       af[0][1]  = LD(Ah, aro, cs1);
      SB0;
      // C2: bfr2, bfr3, af1  (6 reads)
      bfr[2][0] = LD(Bh1, bro, cs0);      bfr[2][1] = LD(Bh1, bro, cs1);
      bfr[3][0] = LD(Bh1, bro + 16, cs0); bfr[3][1] = LD(Bh1, bro + 16, cs1);
      af[1][0]  = LD(Ah, aro + 16, cs0);  af[1][1]  = LD(Ah, aro + 16, cs1);
      SB0;
      // C3: af2 (2)
      af[2][0] = LD(Ah, aro + 32, cs0);   af[2][1] = LD(Ah, aro + 32, cs1);
      SB0;
      // C4: af3 (2) + stage A1,B1(t+1)
      af[3][0] = LD(Ah, aro + 48, cs0);   af[3][1] = LD(Ah, aro + 48, cs1);
      if (s1) { STG_A(1, tt + 1); STG_B(1, tt + 1); }
      SB0;
      // C5: prefetch PH1 f0 (2)
      a1[0] = LD(Ah1, aro, cs0);          a1[1] = LD(Ah1, aro, cs1);
      SB0;
      // interleaved MFMA, counted waits (18 reads outstanding max)
      LGKM(12);                       // C1 done
      __builtin_amdgcn_s_setprio(1);
      MM0(0, 0); MM0(0, 1);
      LGKM(6);                        // C2 done
      MM0(0, 2); MM0(0, 3);
      MM0(1, 0); MM0(1, 1); MM0(1, 2); MM0(1, 3);
      LGKM(4);                        // C3 done
      MM0(2, 0); MM0(2, 1); MM0(2, 2); MM0(2, 3);
      LGKM(2);                        // C4 done (C5 may be in flight)
      MM0(3, 0); MM0(3, 1); MM0(3, 2); MM0(3, 3);
      __builtin_amdgcn_s_setprio(0);
      __builtin_amdgcn_s_barrier();
    }

    // ---------------- PH1: qm = 1 (bfr + a1 held in registers) ----------------
    {
      const u16* Ah1 = &As[p][1][0];
      bf16x8 af1[3][2];   // f = 1..3
      // C2': af1 (2)
      af1[0][0] = LD(Ah1, aro + 16, cs0); af1[0][1] = LD(Ah1, aro + 16, cs1);
      SB0;
      // C3': af2 (2)
      af1[1][0] = LD(Ah1, aro + 32, cs0); af1[1][1] = LD(Ah1, aro + 32, cs1);
      SB0;
      // C4': af3 (2) + stage A0,B0(t+2)
      af1[2][0] = LD(Ah1, aro + 48, cs0); af1[2][1] = LD(Ah1, aro + 48, cs1);
      if (s2) { STG_A(0, tt + 2); STG_B(0, tt + 2); }
      SB0;
      LGKM(6);                        // a1 (prefetched) done
      __builtin_amdgcn_s_setprio(1);
      MM1P(0); MM1P(1); MM1P(2); MM1P(3);
      LGKM(4);                        // af1[0] done
      MM1(1, 0); MM1(1, 1); MM1(1, 2); MM1(1, 3);
      LGKM(2);                        // af1[1] done
      MM1(2, 0); MM1(2, 1); MM1(2, 2); MM1(2, 3);
      LGKM(0);                        // af1[2] done
      MM1(3, 0); MM1(3, 1); MM1(3, 2); MM1(3, 3);
      __builtin_amdgcn_s_setprio(0);
      if (s2) { asm volatile("s_waitcnt vmcnt(4)" ::: "memory"); }
      else    { asm volatile("s_waitcnt vmcnt(0)" ::: "memory"); }
      __builtin_amdgcn_s_barrier();
    }
  }
#undef STG_A
#undef STG_B
#undef MM0
#undef MM1P
#undef MM1
#undef LD

  // epilogue: C/D layout col=lane&15, row=(lane>>4)*4+reg (m89-verified)
  const long long cbase = (long long)bz * sC;
#pragma unroll
  for (int am = 0; am < 8; ++am) {
    const int qm = am >> 2, f = am & 3;
    const int grow0 = m0 + qm * 128 + wm * 64 + f * 16 + l4 * 4;
#pragma unroll
    for (int an = 0; an < 4; ++an) {
      const int gcol = n0 + (an >> 1) * 128 + wn * 32 + (an & 1) * 16 + l15;
      float bv = 0.f;
      if (BIAS) bv = bias[gcol];
#pragma unroll
      for (int r = 0; r < 4; ++r) {
        float v = acc[am][an][r] * alpha + bv;
        long long idx = cbase + (long long)(grow0 + r) * ldc + gcol;
        if constexpr (OUT_BF16) ((u16*)Cv)[idx] = f2bf(v);
        else                    ((float*)Cv)[idx] = v;
      }
    }
  }
}

// ---------------- in-place row softmax over 2048 bf16 cols ----------------
__global__ __launch_bounds__(256) void k_softmax(u16* __restrict__ P) {
  const long long row = blockIdx.x;
  u16* p = P + row * 2048;
  const int t = threadIdx.x;
  us8 v = *reinterpret_cast<const us8*>(&p[t * 8]);
  float f[8];
#pragma unroll
  for (int j = 0; j < 8; ++j) f[j] = bf2f(v[j]);
  float m = f[0];
#pragma unroll
  for (int j = 1; j < 8; ++j) m = fmaxf(m, f[j]);
#pragma unroll
  for (int o = 32; o > 0; o >>= 1) m = fmaxf(m, __shfl_xor(m, o));
  __shared__ float redm[4], reds[4];
  if ((t & 63) == 0) redm[t >> 6] = m;
  __syncthreads();
  m = fmaxf(fmaxf(redm[0], redm[1]), fmaxf(redm[2], redm[3]));
  float s = 0.f;
#pragma unroll
  for (int j = 0; j < 8; ++j) {
    f[j] = __expf(f[j] - m);
    s += f[j];
  }
#pragma unroll
  for (int o = 32; o > 0; o >>= 1) s += __shfl_xor(s, o);
  if ((t & 63) == 0) reds[t >> 6] = s;
  __syncthreads();
  s = reds[0] + reds[1] + reds[2] + reds[3];
  const float inv = 1.0f / s;
  us8 o8;
#pragma unroll
  for (int j = 0; j < 8; ++j) o8[j] = f2bf(f[j] * inv);
  *reinterpret_cast<us8*>(&p[t * 8]) = o8;
}

// ---- tiled bf16 transpose: out[c][r] = in[r][coff+c], per-batch strides ----
__global__ __launch_bounds__(256) void k_transpose(const u16* __restrict__ in,
                                                   u16* __restrict__ out,
                                                   int R, int ld_in, int coff,
                                                   long long sIn, long long sOut) {
  __shared__ u16 tile[32][33];
  const long long ibase = (long long)blockIdx.z * sIn;
  const long long obase = (long long)blockIdx.z * sOut;
  const int c0 = blockIdx.x * 32, r0 = blockIdx.y * 32;
  const int tx = threadIdx.x, ty = threadIdx.y;  // 32 x 8
#pragma unroll
  for (int i = 0; i < 32; i += 8)
    tile[ty + i][tx] = in[ibase + (long long)(r0 + ty + i) * ld_in + coff + c0 + tx];
  __syncthreads();
#pragma unroll
  for (int i = 0; i < 32; i += 8)
    out[obase + (long long)(c0 + ty + i) * R + (r0 + tx)] = tile[tx][ty + i];
}

extern "C" void kernel_launch(void* const* d_in, const int* in_sizes, int n_in,
                              void* d_out, int out_size, void* d_ws, size_t ws_size,
                              hipStream_t stream) {
  (void)in_sizes; (void)n_in; (void)out_size;
  const float* x  = (const float*)d_in[0];
  const float* Wq = (const float*)d_in[1];
  const float* bq = (const float*)d_in[2];
  const float* Wk = (const float*)d_in[3];
  const float* bk = (const float*)d_in[4];
  const float* Wv = (const float*)d_in[5];
  const float* bv = (const float*)d_in[6];
  float* out = (float*)d_out;

  const int B = 4, S = 2048, D = 1024;
  const long long MX = (long long)B * S;  // 8192

  const long long need = MX * D * 2              // xb
                       + 3LL * D * D * 2         // Wqkv (contiguous after xb!)
                       + 3072 * 4                // biasQKV
                       + MX * 3 * D * 2          // QKVb
                       + 2LL * B * S * S * 2     // P, PT (adjacent!)
                       + 2LL * MX * D * 2;       // VT, XT (adjacent!)
  if ((long long)ws_size < need) return;

  char* w = (char*)d_ws;
  u16*   xb   = (u16*)w;   w += MX * D * 2;
  u16*   Wqkv = (u16*)w;   w += 3LL * D * D * 2;  // = xb + MX*D
  float* bQKV = (float*)w; w += 3072 * 4;
  u16*   QKVb = (u16*)w;   w += MX * 3 * D * 2;
  u16*   P    = (u16*)w;   w += (long long)B * S * S * 2;
  u16*   PT   = (u16*)w;   w += (long long)B * S * S * 2;   // = P + 4*S*S
  u16*   VT   = (u16*)w;   w += MX * D * 2;
  u16*   XT   = (u16*)w;   w += MX * D * 2;                 // = VT + 4*D*S
  (void)Wqkv; (void)PT; (void)XT;

  dim3 blk256(256), blk512(512);

  // fused converts (xb and Wqkv contiguous -> single output pointer) + bias
  {
    int xn4 = (int)(MX * D / 4);          // 2097152
    int wn4 = D * D / 4;                  // 262144
    int tot = xn4 + 3 * wn4;
    k_cvt_all<<<dim3((tot + 255) / 256), blk256, 0, stream>>>(x, Wq, Wk, Wv, xb, xn4, wn4);
    k_bias3<<<dim3(12), blk256, 0, stream>>>(bq, bk, bv, bQKV);
  }

  // QKV = X @ Wqkv^T + b : M=8192, N=3072, K=1024 -> QKVb [8192][3072]
  k_gemm8<true, true><<<dim3(12 * 32), blk512, 0, stream>>>(
      xb, Wqkv, QKVb, bQKV, D, D, D, 3 * D, 0, 0, 0, 1.0f, 12, 32);

  // S = (Q @ K^T)/32 per batch: M=N=2048, K=1024 -> P bf16
  k_gemm8<true, false><<<dim3(8 * 8 * 4), blk512, 0, stream>>>(
      QKVb, QKVb + D, P, nullptr, D, 3 * D, 3 * D, S,
      (long long)S * 3 * D, (long long)S * 3 * D, (long long)S * S, 0.03125f, 8, 8);

  // softmax rows in place
  k_softmax<<<dim3((int)(B * S)), blk256, 0, stream>>>(P);

  // transposes: P->PT ; V (QKVb cols 2048..3071) -> VT ; xb -> XT
  {
    dim3 tb(32, 8);
    k_transpose<<<dim3(64, 64, 4), tb, 0, stream>>>(P, PT, S, S, 0,
        (long long)S * S, (long long)S * S);
    k_transpose<<<dim3(32, 64, 4), tb, 0, stream>>>(QKVb, VT, S, 3 * D, 2 * D,
        (long long)S * 3 * D, (long long)D * S);
    k_transpose<<<dim3(32, 64, 4), tb, 0, stream>>>(xb, XT, S, D, 0,
        (long long)S * D, (long long)D * S);
  }

  // merged: z<4 -> out1[z] = P@V = NT(P, VT); z>=4 -> out2[z-4] = NT(PT, XT)
  // (PT = P + 4*S*S, XT = VT + 4*D*S, Cz = out + z*S*D  -- all uniform in z)
  k_gemm8<false, false><<<dim3(4 * 8 * 8), blk512, 0, stream>>>(
      P, VT, out, nullptr, S, S, S, D,
      (long long)S * S, (long long)D * S, (long long)S * D, 1.0f, 4, 8);
}

// Round 6
// 195.979 us; speedup vs baseline: 1.5691x; 1.1374x over previous
//
#include <hip/hip_runtime.h>
#include <hip/hip_bf16.h>
#include <stdint.h>

typedef unsigned short u16;
typedef u16   us8    __attribute__((ext_vector_type(8)));
typedef __bf16 bf16x8 __attribute__((ext_vector_type(8)));
typedef float f32x4  __attribute__((ext_vector_type(4)));

#define DEV static __device__ __forceinline__

DEV u16 f2bf(float f) {                       // fp32 -> bf16 RNE
  uint32_t u = __builtin_bit_cast(uint32_t, f);
  u += 0x7FFFu + ((u >> 16) & 1u);
  return (u16)(u >> 16);
}
DEV float bf2f(u16 s) { return __builtin_bit_cast(float, (uint32_t)s << 16); }

DEV void gl16(const void* g, void* l) {       // async global->LDS, 16B/lane
  __builtin_amdgcn_global_load_lds((const __attribute__((address_space(1))) void*)g,
                                   (__attribute__((address_space(3))) void*)l, 16, 0, 0);
}

// ------- fused fp32 -> bf16 convert for x, Wq, Wk, Wv + bias concat -------
__global__ __launch_bounds__(256) void k_cvt_all(
    const float* __restrict__ x, const float* __restrict__ wq,
    const float* __restrict__ wk, const float* __restrict__ wv,
    const float* __restrict__ bq, const float* __restrict__ bk,
    u16* __restrict__ out, float* __restrict__ bQK, int xn4, int wn4) {
  int i = blockIdx.x * 256 + threadIdx.x;
  const int cvt_tot = xn4 + 3 * wn4;
  if (i < cvt_tot) {
    const float* src;
    int idx;
    if (i < xn4) { src = x; idx = i; }
    else {
      int j = i - xn4;
      if (j < wn4) { src = wq; idx = j; }
      else if (j < 2 * wn4) { src = wk; idx = j - wn4; }
      else { src = wv; idx = j - 2 * wn4; }
    }
    float4 v = reinterpret_cast<const float4*>(src)[idx];
    uint2 o;
    o.x = (uint32_t)f2bf(v.x) | ((uint32_t)f2bf(v.y) << 16);
    o.y = (uint32_t)f2bf(v.z) | ((uint32_t)f2bf(v.w) << 16);
    reinterpret_cast<uint2*>(out)[i] = o;
  } else {
    int j = i - cvt_tot;                 // bias copy: bq(256 f4) bk(256 f4)
    if (j < 256)      reinterpret_cast<float4*>(bQK)[j] = reinterpret_cast<const float4*>(bq)[j];
    else if (j < 512) reinterpret_cast<float4*>(bQK)[j] = reinterpret_cast<const float4*>(bk)[j - 256];
  }
}

// =================== 256x256-tile 2-phase NT GEMM body (R5-proven) ===========
// C[m,n] = alpha * sum_k A[m,k]*B[n,k] (+bias).  A,B bf16 row-major K-contig.
// BM=BN=256, BK=64, 512 threads = 8 waves (2M x 4N), per-wave 128x64 output.
// LDS: As[2 slot][2 half][128x64] = AsB, Bs same = BsB (128 KiB total).
// 2 phases/K-tile split by A-half; stage PH0->A1B1(t+1), PH1->A0B0(t+2);
// boundary vmcnt(4); counted-lgkm read/MFMA interleave; read-side XOR swizzle
// with inverse-swizzled gl16 source. BIAS_MODE: 0 none, 1 col (bias[n]),
// 2 row (bias[m]).
#define SB0 __builtin_amdgcn_sched_barrier(0)
#define LGKM(N) do { asm volatile("s_waitcnt lgkmcnt(" #N ")" ::: "memory"); \
                     __builtin_amdgcn_sched_barrier(0); } while (0)

template <bool OUT_BF16, int BIAS_MODE>
DEV void gemm_body(const u16* __restrict__ A, const u16* __restrict__ B,
                   void* __restrict__ Cv, const float* __restrict__ bias,
                   int K, int lda, int ldb, int ldc, float alpha,
                   int m0, int n0, long long cbase, u16* AsB, u16* BsB) {
  const int t = threadIdx.x;
  const int lane = t & 63;
  const int wid = t >> 6;
  const int wm = wid >> 2;       // 0..1
  const int wn = wid & 3;        // 0..3
  const int l15 = lane & 15, l4 = lane >> 4;

  const int prow = t >> 3;
  const int scol = ((t & 7) ^ (prow & 7)) * 8;
  const u16* Abase = A + (long long)(m0 + prow) * lda + scol;
  const u16* Bbase = B + (long long)(n0 + prow) * ldb + scol;
  const long long a64 = (long long)64 * lda, a128 = (long long)128 * lda;
  const long long b64 = (long long)64 * ldb, b128 = (long long)128 * ldb;
  u16* AsT = AsB + t * 8;
  u16* BsT = BsB + t * 8;

#define STG_A(h, kt) { const u16* s_ = Abase + (h) * a128 + (long long)(kt) * 64; \
    u16* d_ = AsT + (((kt) & 1) * 2 + (h)) * 8192; gl16(s_, d_); gl16(s_ + a64, d_ + 4096); }
#define STG_B(h, kt) { const u16* s_ = Bbase + (h) * b128 + (long long)(kt) * 64; \
    u16* d_ = BsT + (((kt) & 1) * 2 + (h)) * 8192; gl16(s_, d_); gl16(s_ + b64, d_ + 4096); }

  const int aro = wm * 64 + l15;
  const int bro = wn * 32 + l15;
  const int cs0 = ((l4) ^ (l15 & 7)) * 8;
  const int cs1 = ((4 + l4) ^ (l15 & 7)) * 8;
#define LD(base, row, cs) (*(const bf16x8*)&(base)[(row) * 64 + (cs)])

  f32x4 acc[8][4];
#pragma unroll
  for (int i = 0; i < 8; ++i)
#pragma unroll
    for (int j = 0; j < 4; ++j) { f32x4 z = {0.f, 0.f, 0.f, 0.f}; acc[i][j] = z; }

  const int NT = K >> 6;

  STG_A(0, 0); STG_A(1, 0); STG_B(0, 0); STG_B(1, 0);
  STG_A(0, 1); STG_B(0, 1);
  asm volatile("s_waitcnt vmcnt(4)" ::: "memory");
  __builtin_amdgcn_s_barrier();

#define MM0(f_, fn_)                                                            \
  acc[f_][fn_] = __builtin_amdgcn_mfma_f32_16x16x32_bf16(af[f_][0], bfr[fn_][0], acc[f_][fn_], 0, 0, 0); \
  acc[f_][fn_] = __builtin_amdgcn_mfma_f32_16x16x32_bf16(af[f_][1], bfr[fn_][1], acc[f_][fn_], 0, 0, 0)
#define MM1P(fn_)                                                               \
  acc[4][fn_] = __builtin_amdgcn_mfma_f32_16x16x32_bf16(a1[0], bfr[fn_][0], acc[4][fn_], 0, 0, 0); \
  acc[4][fn_] = __builtin_amdgcn_mfma_f32_16x16x32_bf16(a1[1], bfr[fn_][1], acc[4][fn_], 0, 0, 0)
#define MM1(f_, fn_)                                                            \
  acc[4 + (f_)][fn_] = __builtin_amdgcn_mfma_f32_16x16x32_bf16(af1[(f_) - 1][0], bfr[fn_][0], acc[4 + (f_)][fn_], 0, 0, 0); \
  acc[4 + (f_)][fn_] = __builtin_amdgcn_mfma_f32_16x16x32_bf16(af1[(f_) - 1][1], bfr[fn_][1], acc[4 + (f_)][fn_], 0, 0, 0)

  for (int tt = 0; tt < NT; ++tt) {
    const int p = tt & 1;
    const bool s1 = (tt + 1 < NT);
    const bool s2 = (tt + 2 < NT);
    bf16x8 bfr[4][2];
    bf16x8 a1[2];

    // ---------------- PH0: qm = 0 ----------------
    {
      const u16* Ah  = AsB + (p * 2) * 8192;
      const u16* Ah1 = AsB + (p * 2 + 1) * 8192;
      const u16* Bh0 = BsB + (p * 2) * 8192;
      const u16* Bh1 = BsB + (p * 2 + 1) * 8192;
      bf16x8 af[4][2];
      bfr[0][0] = LD(Bh0, bro, cs0);      bfr[0][1] = LD(Bh0, bro, cs1);
      bfr[1][0] = LD(Bh0, bro + 16, cs0); bfr[1][1] = LD(Bh0, bro + 16, cs1);
      af[0][0]  = LD(Ah, aro, cs0);       af[0][1]  = LD(Ah, aro, cs1);
      SB0;
      bfr[2][0] = LD(Bh1, bro, cs0);      bfr[2][1] = LD(Bh1, bro, cs1);
      bfr[3][0] = LD(Bh1, bro + 16, cs0); bfr[3][1] = LD(Bh1, bro + 16, cs1);
      af[1][0]  = LD(Ah, aro + 16, cs0);  af[1][1]  = LD(Ah, aro + 16, cs1);
      SB0;
      af[2][0] = LD(Ah, aro + 32, cs0);   af[2][1] = LD(Ah, aro + 32, cs1);
      SB0;
      af[3][0] = LD(Ah, aro + 48, cs0);   af[3][1] = LD(Ah, aro + 48, cs1);
      if (s1) { STG_A(1, tt + 1); STG_B(1, tt + 1); }
      SB0;
      a1[0] = LD(Ah1, aro, cs0);          a1[1] = LD(Ah1, aro, cs1);
      SB0;
      LGKM(12);
      __builtin_amdgcn_s_setprio(1);
      MM0(0, 0); MM0(0, 1);
      LGKM(6);
      MM0(0, 2); MM0(0, 3);
      MM0(1, 0); MM0(1, 1); MM0(1, 2); MM0(1, 3);
      LGKM(4);
      MM0(2, 0); MM0(2, 1); MM0(2, 2); MM0(2, 3);
      LGKM(2);
      MM0(3, 0); MM0(3, 1); MM0(3, 2); MM0(3, 3);
      __builtin_amdgcn_s_setprio(0);
      __builtin_amdgcn_s_barrier();
    }

    // ---------------- PH1: qm = 1 (bfr + a1 held in registers) ----------------
    {
      const u16* Ah1 = AsB + (p * 2 + 1) * 8192;
      bf16x8 af1[3][2];
      af1[0][0] = LD(Ah1, aro + 16, cs0); af1[0][1] = LD(Ah1, aro + 16, cs1);
      SB0;
      af1[1][0] = LD(Ah1, aro + 32, cs0); af1[1][1] = LD(Ah1, aro + 32, cs1);
      SB0;
      af1[2][0] = LD(Ah1, aro + 48, cs0); af1[2][1] = LD(Ah1, aro + 48, cs1);
      if (s2) { STG_A(0, tt + 2); STG_B(0, tt + 2); }
      SB0;
      LGKM(6);
      __builtin_amdgcn_s_setprio(1);
      MM1P(0); MM1P(1); MM1P(2); MM1P(3);
      LGKM(4);
      MM1(1, 0); MM1(1, 1); MM1(1, 2); MM1(1, 3);
      LGKM(2);
      MM1(2, 0); MM1(2, 1); MM1(2, 2); MM1(2, 3);
      LGKM(0);
      MM1(3, 0); MM1(3, 1); MM1(3, 2); MM1(3, 3);
      __builtin_amdgcn_s_setprio(0);
      if (s2) { asm volatile("s_waitcnt vmcnt(4)" ::: "memory"); }
      else    { asm volatile("s_waitcnt vmcnt(0)" ::: "memory"); }
      __builtin_amdgcn_s_barrier();
    }
  }
#undef STG_A
#undef STG_B
#undef MM0
#undef MM1P
#undef MM1
#undef LD

  // epilogue: C/D layout col=lane&15, row=(lane>>4)*4+reg (m89-verified)
#pragma unroll
  for (int am = 0; am < 8; ++am) {
    const int qm = am >> 2, f = am & 3;
    const int grow0 = m0 + qm * 128 + wm * 64 + f * 16 + l4 * 4;
#pragma unroll
    for (int an = 0; an < 4; ++an) {
      const int gcol = n0 + (an >> 1) * 128 + wn * 32 + (an & 1) * 16 + l15;
      float bc = 0.f;
      if (BIAS_MODE == 1) bc = bias[gcol];
#pragma unroll
      for (int r = 0; r < 4; ++r) {
        float bv_ = (BIAS_MODE == 2) ? bias[grow0 + r] : bc;
        float v = acc[am][an][r] * alpha + bv_;
        long long idx = cbase + (long long)(grow0 + r) * ldc + gcol;
        if constexpr (OUT_BF16) ((u16*)Cv)[idx] = f2bf(v);
        else                    ((float*)Cv)[idx] = v;
      }
    }
  }
}

// ---- standalone batched NT GEMM (scores / outputs), XCD-swizzled ----
template <bool OUT_BF16>
__global__ __launch_bounds__(512, 2) void k_gemm8(
    const u16* __restrict__ A, const u16* __restrict__ B,
    void* __restrict__ Cv, int K, int lda, int ldb, int ldc,
    long long sA, long long sB, long long sC, float alpha, int gx, int gy) {
  __shared__ alignas(16) u16 lds[65536];   // 128 KiB: As | Bs
  const int nwg = gridDim.x;
  int lin = blockIdx.x;
  lin = (lin & 7) * (nwg >> 3) + (lin >> 3);
  const int gxy = gx * gy;
  const int bz = lin / gxy;
  const int rem = lin - bz * gxy;
  const int by = rem / gx;
  const int bx = rem - by * gx;
  gemm_body<OUT_BF16, 0>(A + (long long)bz * sA, B + (long long)bz * sB, Cv,
                         nullptr, K, lda, ldb, ldc, alpha,
                         by * 256, bx * 256, (long long)bz * sC,
                         lds, lds + 32768);
}

// ---- K2: Q/K projection (256 blk) + V^T projection (128 blk) + X^T (2048) ---
// QKb[8192][2048] = X @ [Wq;Wk]^T + b.  VTX[1024][16384]: cols 0..8191 =
// V^T = Wv @ X^T + bv (row bias), cols 8192.. = X^T (pure transpose).
__global__ __launch_bounds__(512, 2) void k_proj(
    const u16* __restrict__ xb, const u16* __restrict__ Wqkv,
    const float* __restrict__ bQK, const float* __restrict__ bv,
    u16* __restrict__ QKb, u16* __restrict__ VTX) {
  __shared__ alignas(16) u16 lds[65536];
  const int bid = blockIdx.x;
  if (bid < 384) {
    int lin = (bid & 7) * 48 + (bid >> 3);    // bijective on [0,384)
    if (lin < 256) {            // Q/K-proj: M=8192 (gy=32), N=2048 (gx=8)
      const int by = lin >> 3, bx = lin & 7;
      gemm_body<true, 1>(xb, Wqkv, QKb, bQK, 1024, 1024, 1024, 2048, 1.0f,
                         by * 256, bx * 256, 0, lds, lds + 32768);
    } else {                    // V^T-proj: M=1024 (gy=4), N=8192 (gx=32)
      const int l2 = lin - 256;
      const int by = l2 >> 5, bx = l2 & 31;
      gemm_body<true, 2>(Wqkv + 2048 * 1024, xb, VTX, bv, 1024, 1024, 1024,
                         16384, 1.0f, by * 256, bx * 256, 0, lds, lds + 32768);
    }
  } else {                      // X^T: 64x64 tiles, 2048 blocks
    const int tb = bid - 384;
    const int r0 = (tb >> 4) * 64, c0 = (tb & 15) * 64;   // row/col in x
    const int tx = threadIdx.x & 63, ty = threadIdx.x >> 6;
    u16* tile = lds;            // [64][65]
#pragma unroll
    for (int i = 0; i < 64; i += 8)
      tile[(ty + i) * 65 + tx] = xb[(long long)(r0 + ty + i) * 1024 + c0 + tx];
    __syncthreads();
#pragma unroll
    for (int i = 0; i < 64; i += 8)
      VTX[(long long)(c0 + ty + i) * 16384 + 8192 + r0 + tx] = tile[tx * 65 + ty + i];
  }
}

// ---------------- in-place row softmax over 2048 bf16 cols ----------------
__global__ __launch_bounds__(256) void k_softmax(u16* __restrict__ P) {
  const long long row = blockIdx.x;
  u16* p = P + row * 2048;
  const int t = threadIdx.x;
  us8 v = *reinterpret_cast<const us8*>(&p[t * 8]);
  float f[8];
#pragma unroll
  for (int j = 0; j < 8; ++j) f[j] = bf2f(v[j]);
  float m = f[0];
#pragma unroll
  for (int j = 1; j < 8; ++j) m = fmaxf(m, f[j]);
#pragma unroll
  for (int o = 32; o > 0; o >>= 1) m = fmaxf(m, __shfl_xor(m, o));
  __shared__ float redm[4], reds[4];
  if ((t & 63) == 0) redm[t >> 6] = m;
  __syncthreads();
  m = fmaxf(fmaxf(redm[0], redm[1]), fmaxf(redm[2], redm[3]));
  float s = 0.f;
#pragma unroll
  for (int j = 0; j < 8; ++j) {
    f[j] = __expf(f[j] - m);
    s += f[j];
  }
#pragma unroll
  for (int o = 32; o > 0; o >>= 1) s += __shfl_xor(s, o);
  if ((t & 63) == 0) reds[t >> 6] = s;
  __syncthreads();
  s = reds[0] + reds[1] + reds[2] + reds[3];
  const float inv = 1.0f / s;
  us8 o8;
#pragma unroll
  for (int j = 0; j < 8; ++j) o8[j] = f2bf(f[j] * inv);
  *reinterpret_cast<us8*>(&p[t * 8]) = o8;
}

// ---- 64x64-tile bf16 transpose (square, same ld both sides, z-batched) ----
__global__ __launch_bounds__(512) void k_tr64(const u16* __restrict__ in,
                                              u16* __restrict__ out,
                                              int ld, long long sIO) {
  __shared__ u16 tile[64 * 65];
  const long long base = (long long)blockIdx.z * sIO;
  const int r0 = blockIdx.y * 64, c0 = blockIdx.x * 64;
  const int tx = threadIdx.x & 63, ty = threadIdx.x >> 6;
#pragma unroll
  for (int i = 0; i < 64; i += 8)
    tile[(ty + i) * 65 + tx] = in[base + (long long)(r0 + ty + i) * ld + c0 + tx];
  __syncthreads();
#pragma unroll
  for (int i = 0; i < 64; i += 8)
    out[base + (long long)(c0 + ty + i) * ld + r0 + tx] = tile[tx * 65 + ty + i];
}

extern "C" void kernel_launch(void* const* d_in, const int* in_sizes, int n_in,
                              void* d_out, int out_size, void* d_ws, size_t ws_size,
                              hipStream_t stream) {
  (void)in_sizes; (void)n_in; (void)out_size;
  const float* x  = (const float*)d_in[0];
  const float* Wq = (const float*)d_in[1];
  const float* bq = (const float*)d_in[2];
  const float* Wk = (const float*)d_in[3];
  const float* bk = (const float*)d_in[4];
  const float* Wv = (const float*)d_in[5];
  const float* bv = (const float*)d_in[6];
  float* out = (float*)d_out;

  const int B = 4, S = 2048, D = 1024;
  const long long MX = (long long)B * S;  // 8192

  const long long need = MX * D * 2              // xb
                       + 3LL * D * D * 2         // Wqkv (contiguous after xb)
                       + 2048 * 4                // bQK
                       + MX * 2 * D * 2          // QKb [8192][2048]
                       + 2LL * B * S * S * 2     // P, PT (adjacent)
                       + (long long)D * 16384 * 2; // VTX [1024][16384]
  if ((long long)ws_size < need) return;

  char* w = (char*)d_ws;
  u16*   xb   = (u16*)w;   w += MX * D * 2;
  u16*   Wqkv = (u16*)w;   w += 3LL * D * D * 2;  // = xb + MX*D (contiguous)
  float* bQK  = (float*)w; w += 2048 * 4;
  u16*   QKb  = (u16*)w;   w += MX * 2 * D * 2;
  u16*   P    = (u16*)w;   w += (long long)B * S * S * 2;
  u16*   PT   = (u16*)w;   w += (long long)B * S * S * 2;   // = P + 4*S*S
  u16*   VTX  = (u16*)w;   w += (long long)D * 16384 * 2;
  (void)Wqkv; (void)PT;

  dim3 blk256(256), blk512(512);

  // K1: fused converts (xb+Wqkv contiguous) + bias concat (bq|bk -> bQK)
  {
    int xn4 = (int)(MX * D / 4);          // 2097152
    int wn4 = D * D / 4;                  // 262144
    int tot = xn4 + 3 * wn4 + 512;        // + 512 float4 bias units
    k_cvt_all<<<dim3((tot + 255) / 256), blk256, 0, stream>>>(
        x, Wq, Wk, Wv, bq, bk, xb, bQK, xn4, wn4);
  }

  // K2: QK-proj + VT-proj + X^T   (384 GEMM blocks + 2048 transpose blocks)
  k_proj<<<dim3(384 + 2048), blk512, 0, stream>>>(xb, Wqkv, bQK, bv, QKb, VTX);

  // K3: S = (Q @ K^T)/32 per batch: M=N=2048, K=1024 -> P bf16
  k_gemm8<true><<<dim3(256), blk512, 0, stream>>>(
      QKb, QKb + D, P, D, 2 * D, 2 * D, S,
      (long long)S * 2 * D, (long long)S * 2 * D, (long long)S * S, 0.03125f, 8, 8);

  // K4: softmax rows in place
  k_softmax<<<dim3((int)(B * S)), blk256, 0, stream>>>(P);

  // K5: P -> PT (64x64 tiles)
  k_tr64<<<dim3(32, 32, 4), blk512, 0, stream>>>(P, PT, S, (long long)S * S);

  // K6: merged z<4 -> out1[z] = NT(P_z, VT_z); z>=4 -> out2[z-4] = NT(PT, XT)
  // A = P + z*S*S (PT contiguous); B = VTX + z*2048 (XT = cols 8192+)
  k_gemm8<false><<<dim3(256), blk512, 0, stream>>>(
      P, VTX, out, S, S, 16384, D,
      (long long)S * S, 2048, (long long)S * D, 1.0f, 4, 8);
}